// Round 19
// baseline (120.182 us; speedup 1.0000x reference)
//
#include <hip/hip_runtime.h>
#include <math.h>

#ifndef __has_builtin
#define __has_builtin(x) 0
#endif

#define NPTS   131072
#define FCH    16
#define CSND   343.0f
#define PB     16           // points per pass
#define BLOCK  256          // 4 waves
#define GRID   512          // 2 WG/CU * 256 CUs, persistent (16 passes/WG)
#define NBLK   (NPTS / PB)  // 8192

// LDS dword offsets (total 14336 dw = 56 KB -> 2 WG/CU):
//   bufA[k]  = k*5120        (80 rows x 64 dw, k=0/1)
//   bufHG[k] = 10240 + k*2048 (16 x 128 dw,    k=0/1)
#define AOFF(k)  ((k) * 5120)
#define HOFF(k)  (10240 + (k) * 2048)

typedef _Float16 half8 __attribute__((ext_vector_type(8)));
typedef _Float16 half2v __attribute__((ext_vector_type(2)));
typedef float    f32x4 __attribute__((ext_vector_type(4)));

static __device__ __forceinline__ half2v pk2h(float a, float b) {
#if __has_builtin(__builtin_amdgcn_cvt_pkrtz)
  return __builtin_bit_cast(half2v, __builtin_amdgcn_cvt_pkrtz(a, b));
#else
  half2v v; v[0] = (_Float16)a; v[1] = (_Float16)b;
  return v;
#endif
}
static __device__ __forceinline__ unsigned pack2(float a, float b) {
  return __builtin_bit_cast(unsigned, pk2h(a, b));
}
#define U32(h) __builtin_bit_cast(unsigned, (h))

// tanh(x) = 1 - 2/(e^{2x}+1): exp+rcp on trans pipe, monotone at +/-inf.
static __device__ __forceinline__ float mytanh(float x) {
#if __has_builtin(__builtin_amdgcn_exp2f)
  float e = __builtin_amdgcn_exp2f(2.885390082f * x);   // 2*log2(e)*x
#else
  float e = __expf(2.0f * x);
#endif
  return fmaf(-2.0f, __builtin_amdgcn_rcpf(e + 1.0f), 1.0f);
}

// R18 BASE (best dispatches: 54.9-55.3us, VGPR=108, clean) + B-phase
// REGISTER SOFTWARE PIPELINE. Mechanism under test: B's ds_reads target
// bufA[cur] while A writes bufA[cur^1]; AOFF(cur) vs AOFF(cur^1) are
// runtime values through a loop-carried XOR -> compiler CANNOT prove
// non-aliasing and must order B's reads after A's writes (lgkmcnt
// serialization), plus each ks-group's MFMAs eat ~120cy of its reads'
// latency. Fix:
//  1) ks=0's 5 fragment loads HOISTED to region start (before phaseA):
//     source-ordered reads-before-writes kills the false dependency; A's
//     ~500cy VALU covers the first-group latency.
//  2) ks-loop 2-deep register double-buffer fA[2][5] (statically indexed
//     after full unroll -- rule #20): ks+1's loads issue under ks's 10
//     MFMAs. +~40 VGPR; LDS (56KB -> 2 WG/CU) stays the binding residency
//     constraint so VGPR up to ~256 is free (R15's trap doesn't apply).
// Null outcome (55+-1) => compiler already disambiguated; latency plateau
// confirmed, declare floor. Everything else byte-for-byte R18:
// [hoisted ks0 reads; A(i+1); D(i-1); B 10-chain pipelined; C] |bar|.

__global__ __launch_bounds__(BLOCK, 1) void helmholtz_kernel(
    const float* __restrict__ x,      // [N,3]
    const float* __restrict__ omega,  // [16]
    const float* __restrict__ W1,     // [3,128]
    const float* __restrict__ b1,     // [128]
    const float* __restrict__ W2,     // [128,128]
    const float* __restrict__ b2,     // [128]
    const float* __restrict__ W3,     // [128,32]
    const float* __restrict__ b3,     // [32]
    float* __restrict__ out)
{
  __shared__ unsigned s_mem[14336];   // 56 KB: 2x bufA + 2x bufHG

  // ---- one-time half-pass stagger: de-convoy the 2 WGs sharing each CU ----
  if ((blockIdx.x >> 8) & 1) {
#pragma unroll
    for (int i = 0; i < 3; i++) __builtin_amdgcn_s_sleep(48);
  }

  const int tid  = threadIdx.x;
  const int w    = tid >> 6;   // wave 0..3
  const int l    = tid & 63;
  const int col  = l & 15;
  const int quad = l >> 4;
  const int nh   = w & 1;      // D re/im tile (waves 0/1)

  // ---- phase A task: point pA (one per thread); units 8g..8g+7 ----
  const int pA = tid >> 4;     // 0..15
  const int g  = tid & 15;
  float wx[8], wy[8], wz[8], bB[8];
#pragma unroll
  for (int u = 0; u < 8; u++) {
    int unit = 8 * g + u;
    wx[u] = W1[unit]; wy[u] = W1[128 + unit]; wz[u] = W1[256 + unit];
    bB[u] = b1[unit];
  }
  // packed W1 copies + folded -2*wq (computed once)
  half2v wxp[4], wyp[4], wzp[4], wqm[4];
#pragma unroll
  for (int j = 0; j < 4; j++) {
    wxp[j] = pk2h(wx[2*j], wx[2*j+1]);
    wyp[j] = pk2h(wy[2*j], wy[2*j+1]);
    wzp[j] = pk2h(wz[2*j], wz[2*j+1]);
    float wq0 = fmaf(wx[2*j],   wx[2*j],   fmaf(wy[2*j],   wy[2*j],   wz[2*j]   * wz[2*j]));
    float wq1 = fmaf(wx[2*j+1], wx[2*j+1], fmaf(wy[2*j+1], wy[2*j+1], wz[2*j+1] * wz[2*j+1]));
    wqm[j] = pk2h(-2.0f * wq0, -2.0f * wq1);
  }
  const half2v hone = {(_Float16)1.0f, (_Float16)1.0f};

  // ---- W2^T fragments: 2 n-tiles (cols 32*w + 16*nt + col), 32 VGPRs ----
  half8 w2f[2][4];
#pragma unroll
  for (int nt = 0; nt < 2; nt++) {
    const int n = 32 * w + 16 * nt + col;
#pragma unroll
    for (int ks = 0; ks < 4; ks++) {
      half8 f;
#pragma unroll
      for (int j8 = 0; j8 < 8; j8++)
        f[j8] = (_Float16)W2[(ks * 32 + (quad << 3) + j8) * 128 + n];
      w2f[nt][ks] = f;
    }
  }
  // ---- W3^T fragment, j-permuted to match HG layout (16 VGPRs) ----
  half8 w3f[4];
#pragma unroll
  for (int ks = 0; ks < 4; ks++) {
    half8 f;
#pragma unroll
    for (int j8 = 0; j8 < 8; j8++) {
      int j = 32 * ks + 16 * (j8 & 1) + 4 * quad + (j8 >> 1);
      f[j8] = (_Float16)W3[j * 32 + 16 * nh + col];
    }
    w3f[ks] = f;
  }

  float b2r[2];
#pragma unroll
  for (int nt = 0; nt < 2; nt++) b2r[nt] = b2[32 * w + 16 * nt + col];
  float k2v = 0.0f;
  if (col >= 1) {
    float om = omega[col] * (1.0f / CSND);
    k2v = om * om;
  }
  const float b3v = b3[16 * nh + col];

  float wsum = 0.0f;
  float xrC[3], xrN[3];

  auto loadX = [&](int blk, float* xr) {
    const float* xb = x + (size_t)blk * PB * 3;
    xr[0] = xb[3 * pA]; xr[1] = xb[3 * pA + 1]; xr[2] = xb[3 * pA + 2];
  };

  auto phaseA = [&](int aOff, const float* xr) {
    const int cbase = ((g ^ pA) << 2) + aOff;
    float x0 = xr[0], x1 = xr[1], x2 = xr[2];
    float t[8];
#pragma unroll
    for (int u = 0; u < 8; u++) {
      float z = fmaf(x0, wx[u], fmaf(x1, wy[u], fmaf(x2, wz[u], bB[u])));
      t[u] = mytanh(z);
    }
    half2v tp[4], sp[4];
#pragma unroll
    for (int j = 0; j < 4; j++) {
      tp[j] = pk2h(t[2*j], t[2*j+1]);
      sp[j] = hone - tp[j] * tp[j];
    }
    uint4 q;
    q = make_uint4(U32(tp[0]), U32(tp[1]), U32(tp[2]), U32(tp[3]));
    *(uint4*)&s_mem[(pA)      * 64 + cbase] = q;
    q = make_uint4(U32(sp[0]*wxp[0]), U32(sp[1]*wxp[1]),
                   U32(sp[2]*wxp[2]), U32(sp[3]*wxp[3]));
    *(uint4*)&s_mem[(16 + pA) * 64 + cbase] = q;
    q = make_uint4(U32(sp[0]*wyp[0]), U32(sp[1]*wyp[1]),
                   U32(sp[2]*wyp[2]), U32(sp[3]*wyp[3]));
    *(uint4*)&s_mem[(32 + pA) * 64 + cbase] = q;
    q = make_uint4(U32(sp[0]*wzp[0]), U32(sp[1]*wzp[1]),
                   U32(sp[2]*wzp[2]), U32(sp[3]*wzp[3]));
    *(uint4*)&s_mem[(48 + pA) * 64 + cbase] = q;
    half2v cp[4];
#pragma unroll
    for (int j = 0; j < 4; j++) cp[j] = (tp[j] * sp[j]) * wqm[j];
    q = make_uint4(U32(cp[0]), U32(cp[1]), U32(cp[2]), U32(cp[3]));
    *(uint4*)&s_mem[(64 + pA) * 64 + cbase] = q;
  };

  auto phaseD = [&](int hOff) {
    if (w < 2) {
      const int pbase = hOff + col * 128;   // row = col; swizzle key col
      f32x4 dy = (f32x4){0.0f, 0.0f, 0.0f, 0.0f};
      f32x4 dl = (f32x4){0.0f, 0.0f, 0.0f, 0.0f};
#pragma unroll
      for (int ks = 0; ks < 4; ks++) {
        int pos = ((((ks << 2) + quad) ^ col) << 2);
        half8 afy = *(const half8*)&s_mem[pbase + pos];
        half8 afl = *(const half8*)&s_mem[pbase + 64 + pos];
        dy = __builtin_amdgcn_mfma_f32_16x16x32_f16(afy, w3f[ks], dy, 0, 0, 0);
        dl = __builtin_amdgcn_mfma_f32_16x16x32_f16(afl, w3f[ks], dl, 0, 0, 0);
      }
      if (col >= 1) {
#pragma unroll
        for (int r = 0; r < 4; r++) {
          float yv  = dy[r] + b3v;
          float res = fmaf(k2v, yv, dl[r]);
          wsum += res * res;
        }
      }
    }
  };

  // ---- prologue: A(first pass) + x prefetch ----
  loadX(blockIdx.x, xrC);
  phaseA(AOFF(0), xrC);
  {
    int nb = blockIdx.x + GRID;
    if (nb < NBLK) loadX(nb, xrN);
  }
  __syncthreads();

  bool hasPrev = false;
  int cur = 0;
  for (int blk = blockIdx.x; blk < NBLK; blk += GRID) {
    int nblk = blk + GRID;
    const int aOff = AOFF(cur);
    // row bases for the 5 A-streams (t, d0, d1, d2, c1)
    const int rb0 = aOff + (col) * 64;
    const int rb1 = aOff + (16 + col) * 64;
    const int rb2 = aOff + (32 + col) * 64;
    const int rb3 = aOff + (48 + col) * 64;
    const int rb4 = aOff + (64 + col) * 64;

    // ---- HOISTED: ks=0 fragment loads BEFORE A's writes (source-ordered
    //      reads-before-writes; latency hides under A's VALU) ----
    half8 fA[2][5];
    {
      int pos = ((quad ^ col) << 2);             // ks=0
      fA[0][0] = *(const half8*)&s_mem[rb0 + pos];
      fA[0][1] = *(const half8*)&s_mem[rb1 + pos];
      fA[0][2] = *(const half8*)&s_mem[rb2 + pos];
      fA[0][3] = *(const half8*)&s_mem[rb3 + pos];
      fA[0][4] = *(const half8*)&s_mem[rb4 + pos];
    }

    // ---- A(i+1) -> bufA[cur^1]  (independent of B/C/D this region) ----
    if (nblk < NBLK) {
      xrC[0] = xrN[0]; xrC[1] = xrN[1]; xrC[2] = xrN[2];
      int n2 = nblk + GRID;
      if (n2 < NBLK) loadX(n2, xrN);
      phaseA(AOFF(cur ^ 1), xrC);
    }
    // ---- D(i-1): reads bufHG[cur^1]  (independent) ----
    if (hasPrev) phaseD(HOFF(cur ^ 1));

    // ---- B(i): 10-chain GEMM, ks-loop software-pipelined in registers ----
    f32x4 accd[3][2], acch[2], accc[2];
#pragma unroll
    for (int d = 0; d < 3; d++)
#pragma unroll
      for (int nt = 0; nt < 2; nt++)
        accd[d][nt] = (f32x4){0.0f, 0.0f, 0.0f, 0.0f};
#pragma unroll
    for (int nt = 0; nt < 2; nt++) {
      acch[nt] = (f32x4){0.0f, 0.0f, 0.0f, 0.0f};
      accc[nt] = (f32x4){0.0f, 0.0f, 0.0f, 0.0f};
    }
#pragma unroll
    for (int ks = 0; ks < 4; ks++) {
      if (ks < 3) {
        int posn = (((((ks + 1) << 2) + quad) ^ col) << 2);
        fA[(ks + 1) & 1][0] = *(const half8*)&s_mem[rb0 + posn];
        fA[(ks + 1) & 1][1] = *(const half8*)&s_mem[rb1 + posn];
        fA[(ks + 1) & 1][2] = *(const half8*)&s_mem[rb2 + posn];
        fA[(ks + 1) & 1][3] = *(const half8*)&s_mem[rb3 + posn];
        fA[(ks + 1) & 1][4] = *(const half8*)&s_mem[rb4 + posn];
      }
      const int b = ks & 1;
      acch[0]    = __builtin_amdgcn_mfma_f32_16x16x32_f16(fA[b][0], w2f[0][ks], acch[0],    0, 0, 0);
      acch[1]    = __builtin_amdgcn_mfma_f32_16x16x32_f16(fA[b][0], w2f[1][ks], acch[1],    0, 0, 0);
      accd[0][0] = __builtin_amdgcn_mfma_f32_16x16x32_f16(fA[b][1], w2f[0][ks], accd[0][0], 0, 0, 0);
      accd[0][1] = __builtin_amdgcn_mfma_f32_16x16x32_f16(fA[b][1], w2f[1][ks], accd[0][1], 0, 0, 0);
      accd[1][0] = __builtin_amdgcn_mfma_f32_16x16x32_f16(fA[b][2], w2f[0][ks], accd[1][0], 0, 0, 0);
      accd[1][1] = __builtin_amdgcn_mfma_f32_16x16x32_f16(fA[b][2], w2f[1][ks], accd[1][1], 0, 0, 0);
      accd[2][0] = __builtin_amdgcn_mfma_f32_16x16x32_f16(fA[b][3], w2f[0][ks], accd[2][0], 0, 0, 0);
      accd[2][1] = __builtin_amdgcn_mfma_f32_16x16x32_f16(fA[b][3], w2f[1][ks], accd[2][1], 0, 0, 0);
      accc[0]    = __builtin_amdgcn_mfma_f32_16x16x32_f16(fA[b][4], w2f[0][ks], accc[0],    0, 0, 0);
      accc[1]    = __builtin_amdgcn_mfma_f32_16x16x32_f16(fA[b][4], w2f[1][ks], accc[1],    0, 0, 0);
    }
    f32x4 bsum[2];
#pragma unroll
    for (int nt = 0; nt < 2; nt++)
      bsum[nt] = accd[0][nt] * accd[0][nt] + accd[1][nt] * accd[1][nt]
               + accd[2][nt] * accd[2][nt];

    // ---- C(i): layer-2 elementwise -> bufHG[cur] (q = 16w+col) ----
    {
      const int hOff = HOFF(cur);
      const int q    = 16 * w + col;
      const int qc   = q >> 2, qr = q & 3;
#pragma unroll
      for (int r = 0; r < 4; r++) {
        int p = (quad << 2) + r;             // point 0..15
        float t2[2], gg[2];
#pragma unroll
        for (int nt = 0; nt < 2; nt++) {
          float z2 = acch[nt][r] + b2r[nt];
          float t  = mytanh(z2);
          float s2 = 1.0f - t * t;
          t2[nt] = t;
          gg[nt] = s2 * (accc[nt][r] - 2.0f * t * bsum[nt][r]);
        }
        int pos = ((qc ^ p) << 2) + qr;
        int pb  = hOff + p * 128;
        s_mem[pb + pos]      = pack2(t2[0], t2[1]);
        s_mem[pb + 64 + pos] = pack2(gg[0], gg[1]);
      }
    }

    hasPrev = true;
    __syncthreads();               // single barrier per pass
    cur ^= 1;
  }
  phaseD(HOFF(cur ^ 1));           // epilogue D (last C wrote bufHG[cur^1])

  // ---- final: wave reduce, one atomic per wave ----
#pragma unroll
  for (int off = 32; off > 0; off >>= 1)
    wsum += __shfl_down(wsum, off, 64);
  if (l == 0)
    atomicAdd(out, wsum * (1.0f / ((float)NPTS * (float)(FCH - 1))));
}

extern "C" void kernel_launch(void* const* d_in, const int* in_sizes, int n_in,
                              void* d_out, int out_size, void* d_ws, size_t ws_size,
                              hipStream_t stream) {
  const float* x     = (const float*)d_in[0];
  const float* omega = (const float*)d_in[1];
  const float* W1    = (const float*)d_in[2];
  const float* b1    = (const float*)d_in[3];
  const float* W2    = (const float*)d_in[4];
  const float* b2    = (const float*)d_in[5];
  const float* W3    = (const float*)d_in[6];
  const float* b3    = (const float*)d_in[7];
  float* out = (float*)d_out;

  (void)hipMemsetAsync(out, 0, sizeof(float), stream);
  helmholtz_kernel<<<GRID, BLOCK, 0, stream>>>(x, omega, W1, b1, W2, b2, W3, b3, out);
}

// Round 21
// 119.123 us; speedup vs baseline: 1.0089x; 1.0089x over previous
//
#include <hip/hip_runtime.h>
#include <math.h>

#ifndef __has_builtin
#define __has_builtin(x) 0
#endif

#define NPTS   131072
#define FCH    16
#define CSND   343.0f
#define PB     16           // points per pass
#define BLOCK  256          // 4 waves
#define GRID   512          // 2 WG/CU * 256 CUs, persistent (16 passes/WG)
#define NBLK   (NPTS / PB)  // 8192

// LDS dword offsets (total 14336 dw = 56 KB -> 2 WG/CU):
//   bufA[k]  = k*5120        (80 rows x 64 dw, k=0/1)
//   bufHG[k] = 10240 + k*2048 (16 x 128 dw,    k=0/1)
#define AOFF(k)  ((k) * 5120)
#define HOFF(k)  (10240 + (k) * 2048)

typedef _Float16 half8 __attribute__((ext_vector_type(8)));
typedef _Float16 half2v __attribute__((ext_vector_type(2)));
typedef float    f32x4 __attribute__((ext_vector_type(4)));

static __device__ __forceinline__ half2v pk2h(float a, float b) {
#if __has_builtin(__builtin_amdgcn_cvt_pkrtz)
  return __builtin_bit_cast(half2v, __builtin_amdgcn_cvt_pkrtz(a, b));
#else
  half2v v; v[0] = (_Float16)a; v[1] = (_Float16)b;
  return v;
#endif
}
static __device__ __forceinline__ unsigned pack2(float a, float b) {
  return __builtin_bit_cast(unsigned, pk2h(a, b));
}
#define U32(h) __builtin_bit_cast(unsigned, (h))

// tanh(x) = 1 - 2/(e^{2x}+1): exp+rcp on trans pipe, monotone at +/-inf.
static __device__ __forceinline__ float mytanh(float x) {
#if __has_builtin(__builtin_amdgcn_exp2f)
  float e = __builtin_amdgcn_exp2f(2.885390082f * x);   // 2*log2(e)*x
#else
  float e = __expf(2.0f * x);
#endif
  return fmaf(-2.0f, __builtin_amdgcn_rcpf(e + 1.0f), 1.0f);
}

// FINAL KERNEL == R18 (session-best, harness-verified in round 18:
// dispatches 54.9-55.3us, bench 118.6us, VGPR=108, zero spills; R20's run
// was an infra GPUAcquisitionTimeout -- resubmitting unchanged).
// R19's register software-pipeline was null-to-negative (57-60us) ->
// reverted. Declared structural constraint (NOT a pipe roofline --
// MfmaUtil 16%, VALUBusy 29%, HBM 0.35%): this phase-chain is
// dependency-latency-bound at ~8.3k cyc/pass elapsed vs ~1.3k issue. 19
// rounds measured and exhausted: occupancy (anti-correlated 14-35%),
// barrier-event halving (slower), LDS traffic -40% (slower), WG shapes
// (slower), setprio (-3.5us), register pipelining (null), spill configs x4
// (fatal). The remaining headroom needs an inline-asm counted-waitcnt
// K-loop (AITER-style full rewrite).
// Structure: 1-barrier pipelined pass, dbuf parity:
//   [A(i+1)->bufA[!c] || D(i-1) rd HG[!c] || B(i) 10-chain; C(i)->HG[c]] |bar|
// B: ONE ks-loop, 10 independent MFMA chains (t x2, d0/d1/d2 x2, c1 x2),
// all 5 ds_read streams issued per ks. Hazards parity-ordered across the
// single barrier. Phases: A packed-f16 (1pt/thread); C q=16w+col; D waves
// 0/1 (w3f j-perm j = 32ks+16(j8&1)+4quad+(j8>>1)).

__global__ __launch_bounds__(BLOCK, 2) void helmholtz_kernel(
    const float* __restrict__ x,      // [N,3]
    const float* __restrict__ omega,  // [16]
    const float* __restrict__ W1,     // [3,128]
    const float* __restrict__ b1,     // [128]
    const float* __restrict__ W2,     // [128,128]
    const float* __restrict__ b2,     // [128]
    const float* __restrict__ W3,     // [128,32]
    const float* __restrict__ b3,     // [32]
    float* __restrict__ out)
{
  __shared__ unsigned s_mem[14336];   // 56 KB: 2x bufA + 2x bufHG

  // ---- one-time half-pass stagger: de-convoy the 2 WGs sharing each CU ----
  if ((blockIdx.x >> 8) & 1) {
#pragma unroll
    for (int i = 0; i < 3; i++) __builtin_amdgcn_s_sleep(48);
  }

  const int tid  = threadIdx.x;
  const int w    = tid >> 6;   // wave 0..3
  const int l    = tid & 63;
  const int col  = l & 15;
  const int quad = l >> 4;
  const int nh   = w & 1;      // D re/im tile (waves 0/1)

  // ---- phase A task: point pA (one per thread); units 8g..8g+7 ----
  const int pA = tid >> 4;     // 0..15
  const int g  = tid & 15;
  float wx[8], wy[8], wz[8], bB[8];
#pragma unroll
  for (int u = 0; u < 8; u++) {
    int unit = 8 * g + u;
    wx[u] = W1[unit]; wy[u] = W1[128 + unit]; wz[u] = W1[256 + unit];
    bB[u] = b1[unit];
  }
  // packed W1 copies + folded -2*wq (computed once)
  half2v wxp[4], wyp[4], wzp[4], wqm[4];
#pragma unroll
  for (int j = 0; j < 4; j++) {
    wxp[j] = pk2h(wx[2*j], wx[2*j+1]);
    wyp[j] = pk2h(wy[2*j], wy[2*j+1]);
    wzp[j] = pk2h(wz[2*j], wz[2*j+1]);
    float wq0 = fmaf(wx[2*j],   wx[2*j],   fmaf(wy[2*j],   wy[2*j],   wz[2*j]   * wz[2*j]));
    float wq1 = fmaf(wx[2*j+1], wx[2*j+1], fmaf(wy[2*j+1], wy[2*j+1], wz[2*j+1] * wz[2*j+1]));
    wqm[j] = pk2h(-2.0f * wq0, -2.0f * wq1);
  }
  const half2v hone = {(_Float16)1.0f, (_Float16)1.0f};

  // ---- W2^T fragments: 2 n-tiles (cols 32*w + 16*nt + col), 32 VGPRs ----
  half8 w2f[2][4];
#pragma unroll
  for (int nt = 0; nt < 2; nt++) {
    const int n = 32 * w + 16 * nt + col;
#pragma unroll
    for (int ks = 0; ks < 4; ks++) {
      half8 f;
#pragma unroll
      for (int j8 = 0; j8 < 8; j8++)
        f[j8] = (_Float16)W2[(ks * 32 + (quad << 3) + j8) * 128 + n];
      w2f[nt][ks] = f;
    }
  }
  // ---- W3^T fragment, j-permuted to match HG layout (16 VGPRs) ----
  half8 w3f[4];
#pragma unroll
  for (int ks = 0; ks < 4; ks++) {
    half8 f;
#pragma unroll
    for (int j8 = 0; j8 < 8; j8++) {
      int j = 32 * ks + 16 * (j8 & 1) + 4 * quad + (j8 >> 1);
      f[j8] = (_Float16)W3[j * 32 + 16 * nh + col];
    }
    w3f[ks] = f;
  }

  float b2r[2];
#pragma unroll
  for (int nt = 0; nt < 2; nt++) b2r[nt] = b2[32 * w + 16 * nt + col];
  float k2v = 0.0f;
  if (col >= 1) {
    float om = omega[col] * (1.0f / CSND);
    k2v = om * om;
  }
  const float b3v = b3[16 * nh + col];

  float wsum = 0.0f;
  float xrC[3], xrN[3];

  auto loadX = [&](int blk, float* xr) {
    const float* xb = x + (size_t)blk * PB * 3;
    xr[0] = xb[3 * pA]; xr[1] = xb[3 * pA + 1]; xr[2] = xb[3 * pA + 2];
  };

  auto phaseA = [&](int aOff, const float* xr) {
    const int cbase = ((g ^ pA) << 2) + aOff;
    float x0 = xr[0], x1 = xr[1], x2 = xr[2];
    float t[8];
#pragma unroll
    for (int u = 0; u < 8; u++) {
      float z = fmaf(x0, wx[u], fmaf(x1, wy[u], fmaf(x2, wz[u], bB[u])));
      t[u] = mytanh(z);
    }
    half2v tp[4], sp[4];
#pragma unroll
    for (int j = 0; j < 4; j++) {
      tp[j] = pk2h(t[2*j], t[2*j+1]);
      sp[j] = hone - tp[j] * tp[j];
    }
    uint4 q;
    q = make_uint4(U32(tp[0]), U32(tp[1]), U32(tp[2]), U32(tp[3]));
    *(uint4*)&s_mem[(pA)      * 64 + cbase] = q;
    q = make_uint4(U32(sp[0]*wxp[0]), U32(sp[1]*wxp[1]),
                   U32(sp[2]*wxp[2]), U32(sp[3]*wxp[3]));
    *(uint4*)&s_mem[(16 + pA) * 64 + cbase] = q;
    q = make_uint4(U32(sp[0]*wyp[0]), U32(sp[1]*wyp[1]),
                   U32(sp[2]*wyp[2]), U32(sp[3]*wyp[3]));
    *(uint4*)&s_mem[(32 + pA) * 64 + cbase] = q;
    q = make_uint4(U32(sp[0]*wzp[0]), U32(sp[1]*wzp[1]),
                   U32(sp[2]*wzp[2]), U32(sp[3]*wzp[3]));
    *(uint4*)&s_mem[(48 + pA) * 64 + cbase] = q;
    half2v cp[4];
#pragma unroll
    for (int j = 0; j < 4; j++) cp[j] = (tp[j] * sp[j]) * wqm[j];
    q = make_uint4(U32(cp[0]), U32(cp[1]), U32(cp[2]), U32(cp[3]));
    *(uint4*)&s_mem[(64 + pA) * 64 + cbase] = q;
  };

  auto phaseD = [&](int hOff) {
    if (w < 2) {
      const int pbase = hOff + col * 128;   // row = col; swizzle key col
      f32x4 dy = (f32x4){0.0f, 0.0f, 0.0f, 0.0f};
      f32x4 dl = (f32x4){0.0f, 0.0f, 0.0f, 0.0f};
#pragma unroll
      for (int ks = 0; ks < 4; ks++) {
        int pos = ((((ks << 2) + quad) ^ col) << 2);
        half8 afy = *(const half8*)&s_mem[pbase + pos];
        half8 afl = *(const half8*)&s_mem[pbase + 64 + pos];
        dy = __builtin_amdgcn_mfma_f32_16x16x32_f16(afy, w3f[ks], dy, 0, 0, 0);
        dl = __builtin_amdgcn_mfma_f32_16x16x32_f16(afl, w3f[ks], dl, 0, 0, 0);
      }
      if (col >= 1) {
#pragma unroll
        for (int r = 0; r < 4; r++) {
          float yv  = dy[r] + b3v;
          float res = fmaf(k2v, yv, dl[r]);
          wsum += res * res;
        }
      }
    }
  };

  // ---- prologue: A(first pass) + x prefetch ----
  loadX(blockIdx.x, xrC);
  phaseA(AOFF(0), xrC);
  {
    int nb = blockIdx.x + GRID;
    if (nb < NBLK) loadX(nb, xrN);
  }
  __syncthreads();

  bool hasPrev = false;
  int cur = 0;
  for (int blk = blockIdx.x; blk < NBLK; blk += GRID) {
    int nblk = blk + GRID;
    // ---- A(i+1) -> bufA[cur^1]  (independent of B/C/D this region) ----
    if (nblk < NBLK) {
      xrC[0] = xrN[0]; xrC[1] = xrN[1]; xrC[2] = xrN[2];
      int n2 = nblk + GRID;
      if (n2 < NBLK) loadX(n2, xrN);
      phaseA(AOFF(cur ^ 1), xrC);
    }
    // ---- D(i-1): reads bufHG[cur^1]  (independent) ----
    if (hasPrev) phaseD(HOFF(cur ^ 1));

    // ---- B(i): MERGED GEMM, 10 independent accumulator chains ----
    const int aOff = AOFF(cur);
    f32x4 accd[3][2], acch[2], accc[2];
#pragma unroll
    for (int d = 0; d < 3; d++)
#pragma unroll
      for (int nt = 0; nt < 2; nt++)
        accd[d][nt] = (f32x4){0.0f, 0.0f, 0.0f, 0.0f};
#pragma unroll
    for (int nt = 0; nt < 2; nt++) {
      acch[nt] = (f32x4){0.0f, 0.0f, 0.0f, 0.0f};
      accc[nt] = (f32x4){0.0f, 0.0f, 0.0f, 0.0f};
    }
    {
      const int rbt = aOff + (col) * 64;        // t  rows (v=0)
      const int rb0 = aOff + (16 + col) * 64;   // d0 rows (v=1)
      const int rb1 = aOff + (32 + col) * 64;   // d1 rows (v=2)
      const int rb2 = aOff + (48 + col) * 64;   // d2 rows (v=3)
      const int rbc = aOff + (64 + col) * 64;   // c1 rows (v=4)
#pragma unroll
      for (int ks = 0; ks < 4; ks++) {
        int pos = ((((ks << 2) + quad) ^ col) << 2);
        half8 aft = *(const half8*)&s_mem[rbt + pos];
        half8 af0 = *(const half8*)&s_mem[rb0 + pos];
        half8 af1 = *(const half8*)&s_mem[rb1 + pos];
        half8 af2 = *(const half8*)&s_mem[rb2 + pos];
        half8 afc = *(const half8*)&s_mem[rbc + pos];
        acch[0]    = __builtin_amdgcn_mfma_f32_16x16x32_f16(aft, w2f[0][ks], acch[0],    0, 0, 0);
        acch[1]    = __builtin_amdgcn_mfma_f32_16x16x32_f16(aft, w2f[1][ks], acch[1],    0, 0, 0);
        accd[0][0] = __builtin_amdgcn_mfma_f32_16x16x32_f16(af0, w2f[0][ks], accd[0][0], 0, 0, 0);
        accd[0][1] = __builtin_amdgcn_mfma_f32_16x16x32_f16(af0, w2f[1][ks], accd[0][1], 0, 0, 0);
        accd[1][0] = __builtin_amdgcn_mfma_f32_16x16x32_f16(af1, w2f[0][ks], accd[1][0], 0, 0, 0);
        accd[1][1] = __builtin_amdgcn_mfma_f32_16x16x32_f16(af1, w2f[1][ks], accd[1][1], 0, 0, 0);
        accd[2][0] = __builtin_amdgcn_mfma_f32_16x16x32_f16(af2, w2f[0][ks], accd[2][0], 0, 0, 0);
        accd[2][1] = __builtin_amdgcn_mfma_f32_16x16x32_f16(af2, w2f[1][ks], accd[2][1], 0, 0, 0);
        accc[0]    = __builtin_amdgcn_mfma_f32_16x16x32_f16(afc, w2f[0][ks], accc[0],    0, 0, 0);
        accc[1]    = __builtin_amdgcn_mfma_f32_16x16x32_f16(afc, w2f[1][ks], accc[1],    0, 0, 0);
      }
    }
    f32x4 bsum[2];
#pragma unroll
    for (int nt = 0; nt < 2; nt++)
      bsum[nt] = accd[0][nt] * accd[0][nt] + accd[1][nt] * accd[1][nt]
               + accd[2][nt] * accd[2][nt];

    // ---- C(i): layer-2 elementwise -> bufHG[cur] (q = 16w+col) ----
    {
      const int hOff = HOFF(cur);
      const int q    = 16 * w + col;
      const int qc   = q >> 2, qr = q & 3;
#pragma unroll
      for (int r = 0; r < 4; r++) {
        int p = (quad << 2) + r;             // point 0..15
        float t2[2], gg[2];
#pragma unroll
        for (int nt = 0; nt < 2; nt++) {
          float z2 = acch[nt][r] + b2r[nt];
          float t  = mytanh(z2);
          float s2 = 1.0f - t * t;
          t2[nt] = t;
          gg[nt] = s2 * (accc[nt][r] - 2.0f * t * bsum[nt][r]);
        }
        int pos = ((qc ^ p) << 2) + qr;
        int pb  = hOff + p * 128;
        s_mem[pb + pos]      = pack2(t2[0], t2[1]);
        s_mem[pb + 64 + pos] = pack2(gg[0], gg[1]);
      }
    }

    hasPrev = true;
    __syncthreads();               // single barrier per pass
    cur ^= 1;
  }
  phaseD(HOFF(cur ^ 1));           // epilogue D (last C wrote bufHG[cur^1])

  // ---- final: wave reduce, one atomic per wave ----
#pragma unroll
  for (int off = 32; off > 0; off >>= 1)
    wsum += __shfl_down(wsum, off, 64);
  if (l == 0)
    atomicAdd(out, wsum * (1.0f / ((float)NPTS * (float)(FCH - 1))));
}

extern "C" void kernel_launch(void* const* d_in, const int* in_sizes, int n_in,
                              void* d_out, int out_size, void* d_ws, size_t ws_size,
                              hipStream_t stream) {
  const float* x     = (const float*)d_in[0];
  const float* omega = (const float*)d_in[1];
  const float* W1    = (const float*)d_in[2];
  const float* b1    = (const float*)d_in[3];
  const float* W2    = (const float*)d_in[4];
  const float* b2    = (const float*)d_in[5];
  const float* W3    = (const float*)d_in[6];
  const float* b3    = (const float*)d_in[7];
  float* out = (float*)d_out;

  (void)hipMemsetAsync(out, 0, sizeof(float), stream);
  helmholtz_kernel<<<GRID, BLOCK, 0, stream>>>(x, omega, W1, b1, W2, b2, W3, b3, out);
}

// Round 22
// 117.498 us; speedup vs baseline: 1.0228x; 1.0138x over previous
//
#include <hip/hip_runtime.h>
#include <math.h>

#ifndef __has_builtin
#define __has_builtin(x) 0
#endif

#define NPTS   131072
#define FCH    16
#define CSND   343.0f
#define PB     16           // points per pass
#define BLOCK  256          // 4 waves
#define GRID   512          // 2 WG/CU * 256 CUs, persistent (16 passes/WG)
#define NBLK   (NPTS / PB)  // 8192

// LDS dword offsets (total 14336 dw = 56 KB -> 2 WG/CU):
//   bufA[k]  = k*5120        (80 rows x 64 dw, k=0/1)
//   bufHG[k] = 10240 + k*2048 (16 x 128 dw,    k=0/1)
#define AOFF(k)  ((k) * 5120)
#define HOFF(k)  (10240 + (k) * 2048)

typedef _Float16 half8 __attribute__((ext_vector_type(8)));
typedef _Float16 half2v __attribute__((ext_vector_type(2)));
typedef float    f32x4 __attribute__((ext_vector_type(4)));

static __device__ __forceinline__ half2v pk2h(float a, float b) {
#if __has_builtin(__builtin_amdgcn_cvt_pkrtz)
  return __builtin_bit_cast(half2v, __builtin_amdgcn_cvt_pkrtz(a, b));
#else
  half2v v; v[0] = (_Float16)a; v[1] = (_Float16)b;
  return v;
#endif
}
static __device__ __forceinline__ unsigned pack2(float a, float b) {
  return __builtin_bit_cast(unsigned, pk2h(a, b));
}
#define U32(h) __builtin_bit_cast(unsigned, (h))

// tanh(x) = 1 - 2/(e^{2x}+1): exp+rcp on trans pipe, monotone at +/-inf.
static __device__ __forceinline__ float mytanh(float x) {
#if __has_builtin(__builtin_amdgcn_exp2f)
  float e = __builtin_amdgcn_exp2f(2.885390082f * x);   // 2*log2(e)*x
#else
  float e = __expf(2.0f * x);
#endif
  return fmaf(-2.0f, __builtin_amdgcn_rcpf(e + 1.0f), 1.0f);
}

// FINAL KERNEL (== R18, confirmed twice: R18 and R21). Steady dispatches
// 55.0-55.3us, bench 117.4-119.1us, VGPR=108, zero spills. Session arc:
// 72us (R0 baseline) -> 59.4 (R6: packed-f16 A + stagger) -> 56.5 (R9:
// 1-barrier pipelined dbuf) -> 55.1 (R18: 10-chain merged B, no setprio).
// Declared constraint (NOT a pipe roofline -- MfmaUtil 16%, VALUBusy 30%,
// HBM 0.35%): dependency-latency plateau of this phase-chain at HIP source
// level (~8.3k cyc/pass elapsed vs ~1.3k issue). Measured-and-exhausted:
// occupancy (anti-correlated 14-35%), barrier-event halving (slower), LDS
// traffic -40% (slower), WG shapes (slower), setprio (-3.5us), register
// pipelining (null, pre-registered), spill regimes x4 (fatal). Remaining
// headroom requires an inline-asm counted-waitcnt loop (AITER-style).
// Structure: 1-barrier pipelined pass, dbuf parity:
//   [A(i+1)->bufA[!c] || D(i-1) rd HG[!c] || B(i) 10-chain; C(i)->HG[c]] |bar|
// B: ONE ks-loop, 10 independent MFMA chains (t x2, d0/d1/d2 x2, c1 x2),
// all 5 ds_read streams issued per ks. Hazards parity-ordered across the
// single barrier. Phases: A packed-f16 (1pt/thread); C q=16w+col; D waves
// 0/1 (w3f j-perm j = 32ks+16(j8&1)+4quad+(j8>>1)).

__global__ __launch_bounds__(BLOCK, 2) void helmholtz_kernel(
    const float* __restrict__ x,      // [N,3]
    const float* __restrict__ omega,  // [16]
    const float* __restrict__ W1,     // [3,128]
    const float* __restrict__ b1,     // [128]
    const float* __restrict__ W2,     // [128,128]
    const float* __restrict__ b2,     // [128]
    const float* __restrict__ W3,     // [128,32]
    const float* __restrict__ b3,     // [32]
    float* __restrict__ out)
{
  __shared__ unsigned s_mem[14336];   // 56 KB: 2x bufA + 2x bufHG

  // ---- one-time half-pass stagger: de-convoy the 2 WGs sharing each CU ----
  if ((blockIdx.x >> 8) & 1) {
#pragma unroll
    for (int i = 0; i < 3; i++) __builtin_amdgcn_s_sleep(48);
  }

  const int tid  = threadIdx.x;
  const int w    = tid >> 6;   // wave 0..3
  const int l    = tid & 63;
  const int col  = l & 15;
  const int quad = l >> 4;
  const int nh   = w & 1;      // D re/im tile (waves 0/1)

  // ---- phase A task: point pA (one per thread); units 8g..8g+7 ----
  const int pA = tid >> 4;     // 0..15
  const int g  = tid & 15;
  float wx[8], wy[8], wz[8], bB[8];
#pragma unroll
  for (int u = 0; u < 8; u++) {
    int unit = 8 * g + u;
    wx[u] = W1[unit]; wy[u] = W1[128 + unit]; wz[u] = W1[256 + unit];
    bB[u] = b1[unit];
  }
  // packed W1 copies + folded -2*wq (computed once)
  half2v wxp[4], wyp[4], wzp[4], wqm[4];
#pragma unroll
  for (int j = 0; j < 4; j++) {
    wxp[j] = pk2h(wx[2*j], wx[2*j+1]);
    wyp[j] = pk2h(wy[2*j], wy[2*j+1]);
    wzp[j] = pk2h(wz[2*j], wz[2*j+1]);
    float wq0 = fmaf(wx[2*j],   wx[2*j],   fmaf(wy[2*j],   wy[2*j],   wz[2*j]   * wz[2*j]));
    float wq1 = fmaf(wx[2*j+1], wx[2*j+1], fmaf(wy[2*j+1], wy[2*j+1], wz[2*j+1] * wz[2*j+1]));
    wqm[j] = pk2h(-2.0f * wq0, -2.0f * wq1);
  }
  const half2v hone = {(_Float16)1.0f, (_Float16)1.0f};

  // ---- W2^T fragments: 2 n-tiles (cols 32*w + 16*nt + col), 32 VGPRs ----
  half8 w2f[2][4];
#pragma unroll
  for (int nt = 0; nt < 2; nt++) {
    const int n = 32 * w + 16 * nt + col;
#pragma unroll
    for (int ks = 0; ks < 4; ks++) {
      half8 f;
#pragma unroll
      for (int j8 = 0; j8 < 8; j8++)
        f[j8] = (_Float16)W2[(ks * 32 + (quad << 3) + j8) * 128 + n];
      w2f[nt][ks] = f;
    }
  }
  // ---- W3^T fragment, j-permuted to match HG layout (16 VGPRs) ----
  half8 w3f[4];
#pragma unroll
  for (int ks = 0; ks < 4; ks++) {
    half8 f;
#pragma unroll
    for (int j8 = 0; j8 < 8; j8++) {
      int j = 32 * ks + 16 * (j8 & 1) + 4 * quad + (j8 >> 1);
      f[j8] = (_Float16)W3[j * 32 + 16 * nh + col];
    }
    w3f[ks] = f;
  }

  float b2r[2];
#pragma unroll
  for (int nt = 0; nt < 2; nt++) b2r[nt] = b2[32 * w + 16 * nt + col];
  float k2v = 0.0f;
  if (col >= 1) {
    float om = omega[col] * (1.0f / CSND);
    k2v = om * om;
  }
  const float b3v = b3[16 * nh + col];

  float wsum = 0.0f;
  float xrC[3], xrN[3];

  auto loadX = [&](int blk, float* xr) {
    const float* xb = x + (size_t)blk * PB * 3;
    xr[0] = xb[3 * pA]; xr[1] = xb[3 * pA + 1]; xr[2] = xb[3 * pA + 2];
  };

  auto phaseA = [&](int aOff, const float* xr) {
    const int cbase = ((g ^ pA) << 2) + aOff;
    float x0 = xr[0], x1 = xr[1], x2 = xr[2];
    float t[8];
#pragma unroll
    for (int u = 0; u < 8; u++) {
      float z = fmaf(x0, wx[u], fmaf(x1, wy[u], fmaf(x2, wz[u], bB[u])));
      t[u] = mytanh(z);
    }
    half2v tp[4], sp[4];
#pragma unroll
    for (int j = 0; j < 4; j++) {
      tp[j] = pk2h(t[2*j], t[2*j+1]);
      sp[j] = hone - tp[j] * tp[j];
    }
    uint4 q;
    q = make_uint4(U32(tp[0]), U32(tp[1]), U32(tp[2]), U32(tp[3]));
    *(uint4*)&s_mem[(pA)      * 64 + cbase] = q;
    q = make_uint4(U32(sp[0]*wxp[0]), U32(sp[1]*wxp[1]),
                   U32(sp[2]*wxp[2]), U32(sp[3]*wxp[3]));
    *(uint4*)&s_mem[(16 + pA) * 64 + cbase] = q;
    q = make_uint4(U32(sp[0]*wyp[0]), U32(sp[1]*wyp[1]),
                   U32(sp[2]*wyp[2]), U32(sp[3]*wyp[3]));
    *(uint4*)&s_mem[(32 + pA) * 64 + cbase] = q;
    q = make_uint4(U32(sp[0]*wzp[0]), U32(sp[1]*wzp[1]),
                   U32(sp[2]*wzp[2]), U32(sp[3]*wzp[3]));
    *(uint4*)&s_mem[(48 + pA) * 64 + cbase] = q;
    half2v cp[4];
#pragma unroll
    for (int j = 0; j < 4; j++) cp[j] = (tp[j] * sp[j]) * wqm[j];
    q = make_uint4(U32(cp[0]), U32(cp[1]), U32(cp[2]), U32(cp[3]));
    *(uint4*)&s_mem[(64 + pA) * 64 + cbase] = q;
  };

  auto phaseD = [&](int hOff) {
    if (w < 2) {
      const int pbase = hOff + col * 128;   // row = col; swizzle key col
      f32x4 dy = (f32x4){0.0f, 0.0f, 0.0f, 0.0f};
      f32x4 dl = (f32x4){0.0f, 0.0f, 0.0f, 0.0f};
#pragma unroll
      for (int ks = 0; ks < 4; ks++) {
        int pos = ((((ks << 2) + quad) ^ col) << 2);
        half8 afy = *(const half8*)&s_mem[pbase + pos];
        half8 afl = *(const half8*)&s_mem[pbase + 64 + pos];
        dy = __builtin_amdgcn_mfma_f32_16x16x32_f16(afy, w3f[ks], dy, 0, 0, 0);
        dl = __builtin_amdgcn_mfma_f32_16x16x32_f16(afl, w3f[ks], dl, 0, 0, 0);
      }
      if (col >= 1) {
#pragma unroll
        for (int r = 0; r < 4; r++) {
          float yv  = dy[r] + b3v;
          float res = fmaf(k2v, yv, dl[r]);
          wsum += res * res;
        }
      }
    }
  };

  // ---- prologue: A(first pass) + x prefetch ----
  loadX(blockIdx.x, xrC);
  phaseA(AOFF(0), xrC);
  {
    int nb = blockIdx.x + GRID;
    if (nb < NBLK) loadX(nb, xrN);
  }
  __syncthreads();

  bool hasPrev = false;
  int cur = 0;
  for (int blk = blockIdx.x; blk < NBLK; blk += GRID) {
    int nblk = blk + GRID;
    // ---- A(i+1) -> bufA[cur^1]  (independent of B/C/D this region) ----
    if (nblk < NBLK) {
      xrC[0] = xrN[0]; xrC[1] = xrN[1]; xrC[2] = xrN[2];
      int n2 = nblk + GRID;
      if (n2 < NBLK) loadX(n2, xrN);
      phaseA(AOFF(cur ^ 1), xrC);
    }
    // ---- D(i-1): reads bufHG[cur^1]  (independent) ----
    if (hasPrev) phaseD(HOFF(cur ^ 1));

    // ---- B(i): MERGED GEMM, 10 independent accumulator chains ----
    const int aOff = AOFF(cur);
    f32x4 accd[3][2], acch[2], accc[2];
#pragma unroll
    for (int d = 0; d < 3; d++)
#pragma unroll
      for (int nt = 0; nt < 2; nt++)
        accd[d][nt] = (f32x4){0.0f, 0.0f, 0.0f, 0.0f};
#pragma unroll
    for (int nt = 0; nt < 2; nt++) {
      acch[nt] = (f32x4){0.0f, 0.0f, 0.0f, 0.0f};
      accc[nt] = (f32x4){0.0f, 0.0f, 0.0f, 0.0f};
    }
    {
      const int rbt = aOff + (col) * 64;        // t  rows (v=0)
      const int rb0 = aOff + (16 + col) * 64;   // d0 rows (v=1)
      const int rb1 = aOff + (32 + col) * 64;   // d1 rows (v=2)
      const int rb2 = aOff + (48 + col) * 64;   // d2 rows (v=3)
      const int rbc = aOff + (64 + col) * 64;   // c1 rows (v=4)
#pragma unroll
      for (int ks = 0; ks < 4; ks++) {
        int pos = ((((ks << 2) + quad) ^ col) << 2);
        half8 aft = *(const half8*)&s_mem[rbt + pos];
        half8 af0 = *(const half8*)&s_mem[rb0 + pos];
        half8 af1 = *(const half8*)&s_mem[rb1 + pos];
        half8 af2 = *(const half8*)&s_mem[rb2 + pos];
        half8 afc = *(const half8*)&s_mem[rbc + pos];
        acch[0]    = __builtin_amdgcn_mfma_f32_16x16x32_f16(aft, w2f[0][ks], acch[0],    0, 0, 0);
        acch[1]    = __builtin_amdgcn_mfma_f32_16x16x32_f16(aft, w2f[1][ks], acch[1],    0, 0, 0);
        accd[0][0] = __builtin_amdgcn_mfma_f32_16x16x32_f16(af0, w2f[0][ks], accd[0][0], 0, 0, 0);
        accd[0][1] = __builtin_amdgcn_mfma_f32_16x16x32_f16(af0, w2f[1][ks], accd[0][1], 0, 0, 0);
        accd[1][0] = __builtin_amdgcn_mfma_f32_16x16x32_f16(af1, w2f[0][ks], accd[1][0], 0, 0, 0);
        accd[1][1] = __builtin_amdgcn_mfma_f32_16x16x32_f16(af1, w2f[1][ks], accd[1][1], 0, 0, 0);
        accd[2][0] = __builtin_amdgcn_mfma_f32_16x16x32_f16(af2, w2f[0][ks], accd[2][0], 0, 0, 0);
        accd[2][1] = __builtin_amdgcn_mfma_f32_16x16x32_f16(af2, w2f[1][ks], accd[2][1], 0, 0, 0);
        accc[0]    = __builtin_amdgcn_mfma_f32_16x16x32_f16(afc, w2f[0][ks], accc[0],    0, 0, 0);
        accc[1]    = __builtin_amdgcn_mfma_f32_16x16x32_f16(afc, w2f[1][ks], accc[1],    0, 0, 0);
      }
    }
    f32x4 bsum[2];
#pragma unroll
    for (int nt = 0; nt < 2; nt++)
      bsum[nt] = accd[0][nt] * accd[0][nt] + accd[1][nt] * accd[1][nt]
               + accd[2][nt] * accd[2][nt];

    // ---- C(i): layer-2 elementwise -> bufHG[cur] (q = 16w+col) ----
    {
      const int hOff = HOFF(cur);
      const int q    = 16 * w + col;
      const int qc   = q >> 2, qr = q & 3;
#pragma unroll
      for (int r = 0; r < 4; r++) {
        int p = (quad << 2) + r;             // point 0..15
        float t2[2], gg[2];
#pragma unroll
        for (int nt = 0; nt < 2; nt++) {
          float z2 = acch[nt][r] + b2r[nt];
          float t  = mytanh(z2);
          float s2 = 1.0f - t * t;
          t2[nt] = t;
          gg[nt] = s2 * (accc[nt][r] - 2.0f * t * bsum[nt][r]);
        }
        int pos = ((qc ^ p) << 2) + qr;
        int pb  = hOff + p * 128;
        s_mem[pb + pos]      = pack2(t2[0], t2[1]);
        s_mem[pb + 64 + pos] = pack2(gg[0], gg[1]);
      }
    }

    hasPrev = true;
    __syncthreads();               // single barrier per pass
    cur ^= 1;
  }
  phaseD(HOFF(cur ^ 1));           // epilogue D (last C wrote bufHG[cur^1])

  // ---- final: wave reduce, one atomic per wave ----
#pragma unroll
  for (int off = 32; off > 0; off >>= 1)
    wsum += __shfl_down(wsum, off, 64);
  if (l == 0)
    atomicAdd(out, wsum * (1.0f / ((float)NPTS * (float)(FCH - 1))));
}

extern "C" void kernel_launch(void* const* d_in, const int* in_sizes, int n_in,
                              void* d_out, int out_size, void* d_ws, size_t ws_size,
                              hipStream_t stream) {
  const float* x     = (const float*)d_in[0];
  const float* omega = (const float*)d_in[1];
  const float* W1    = (const float*)d_in[2];
  const float* b1    = (const float*)d_in[3];
  const float* W2    = (const float*)d_in[4];
  const float* b2    = (const float*)d_in[5];
  const float* W3    = (const float*)d_in[6];
  const float* b3    = (const float*)d_in[7];
  float* out = (float*)d_out;

  (void)hipMemsetAsync(out, 0, sizeof(float), stream);
  helmholtz_kernel<<<GRID, BLOCK, 0, stream>>>(x, omega, W1, b1, W2, b2, W3, b3, out);
}

// Round 23
// 117.180 us; speedup vs baseline: 1.0256x; 1.0027x over previous
//
#include <hip/hip_runtime.h>
#include <math.h>

#ifndef __has_builtin
#define __has_builtin(x) 0
#endif

#define NPTS   131072
#define FCH    16
#define CSND   343.0f
#define PB     16           // points per pass
#define BLOCK  256          // 4 waves
#define GRID   512          // 2 WG/CU * 256 CUs, persistent (16 passes/WG)
#define NBLK   (NPTS / PB)  // 8192

// LDS dword offsets (total 14336 dw = 56 KB -> 2 WG/CU):
//   bufA[k]  = k*5120        (80 rows x 64 dw, k=0/1)
//   bufHG[k] = 10240 + k*2048 (16 x 128 dw,    k=0/1)
#define AOFF(k)  ((k) * 5120)
#define HOFF(k)  (10240 + (k) * 2048)

typedef _Float16 half8 __attribute__((ext_vector_type(8)));
typedef _Float16 half2v __attribute__((ext_vector_type(2)));
typedef float    f32x4 __attribute__((ext_vector_type(4)));

static __device__ __forceinline__ half2v pk2h(float a, float b) {
#if __has_builtin(__builtin_amdgcn_cvt_pkrtz)
  return __builtin_bit_cast(half2v, __builtin_amdgcn_cvt_pkrtz(a, b));
#else
  half2v v; v[0] = (_Float16)a; v[1] = (_Float16)b;
  return v;
#endif
}
static __device__ __forceinline__ unsigned pack2(float a, float b) {
  return __builtin_bit_cast(unsigned, pk2h(a, b));
}
#define U32(h) __builtin_bit_cast(unsigned, (h))

// tanh(x) = 1 - 2/(e^{2x}+1): exp+rcp on trans pipe, monotone at +/-inf.
static __device__ __forceinline__ float mytanh(float x) {
#if __has_builtin(__builtin_amdgcn_exp2f)
  float e = __builtin_amdgcn_exp2f(2.885390082f * x);   // 2*log2(e)*x
#else
  float e = __expf(2.0f * x);
#endif
  return fmaf(-2.0f, __builtin_amdgcn_rcpf(e + 1.0f), 1.0f);
}

// R18 BASE (triple-confirmed: 54.9-56.5us dispatches, VGPR=108, clean) +
// D FUSED INTO B's ks-LOOP ON ALL 4 WAVES. Mechanism: R18's D(i-1) sits in
// `if (w<2)` -- a separate basic block BEFORE B, so (1) GCN's per-block
// scheduler can't interleave D's ~300cy (8 ds_read ~120cy + two 4-deep
// MFMA chains) with B's independent streams, and (2) waves 0/1 do strictly
// more work than 2/3 -> every pass's barrier syncs to the stragglers
// (~300cy x 16 passes ~= 2us pure imbalance). Fusion: all 4 waves run D's
// loads+MFMAs inside B's ks-loop (same pos formula); waves 2/3 compute
// duplicate dy/dl (w3f built with nh=w&1 duplicates nh=0/1), discarded by
// gating wsum accumulation with (hasPrev && w<2). All waves now execute
// identical straight-line code. Cost: +16% LDS reads, +9% MFMA issue --
// both pipes far from their limits (R15: LDS traffic not binding). First
// pass reads uninitialized HG -> harmless, results gated off.
// Everything else byte-for-byte R18: 1-barrier pipelined pass, dbuf parity:
//   [A(i+1)->bufA[!c] || B(i)+D(i-1) fused 12-chain; C(i)->HG[c]] |bar|

__global__ __launch_bounds__(BLOCK, 2) void helmholtz_kernel(
    const float* __restrict__ x,      // [N,3]
    const float* __restrict__ omega,  // [16]
    const float* __restrict__ W1,     // [3,128]
    const float* __restrict__ b1,     // [128]
    const float* __restrict__ W2,     // [128,128]
    const float* __restrict__ b2,     // [128]
    const float* __restrict__ W3,     // [128,32]
    const float* __restrict__ b3,     // [32]
    float* __restrict__ out)
{
  __shared__ unsigned s_mem[14336];   // 56 KB: 2x bufA + 2x bufHG

  // ---- one-time half-pass stagger: de-convoy the 2 WGs sharing each CU ----
  if ((blockIdx.x >> 8) & 1) {
#pragma unroll
    for (int i = 0; i < 3; i++) __builtin_amdgcn_s_sleep(48);
  }

  const int tid  = threadIdx.x;
  const int w    = tid >> 6;   // wave 0..3
  const int l    = tid & 63;
  const int col  = l & 15;
  const int quad = l >> 4;
  const int nh   = w & 1;      // D re/im tile (waves 2/3 duplicate 0/1)

  // ---- phase A task: point pA (one per thread); units 8g..8g+7 ----
  const int pA = tid >> 4;     // 0..15
  const int g  = tid & 15;
  float wx[8], wy[8], wz[8], bB[8];
#pragma unroll
  for (int u = 0; u < 8; u++) {
    int unit = 8 * g + u;
    wx[u] = W1[unit]; wy[u] = W1[128 + unit]; wz[u] = W1[256 + unit];
    bB[u] = b1[unit];
  }
  // packed W1 copies + folded -2*wq (computed once)
  half2v wxp[4], wyp[4], wzp[4], wqm[4];
#pragma unroll
  for (int j = 0; j < 4; j++) {
    wxp[j] = pk2h(wx[2*j], wx[2*j+1]);
    wyp[j] = pk2h(wy[2*j], wy[2*j+1]);
    wzp[j] = pk2h(wz[2*j], wz[2*j+1]);
    float wq0 = fmaf(wx[2*j],   wx[2*j],   fmaf(wy[2*j],   wy[2*j],   wz[2*j]   * wz[2*j]));
    float wq1 = fmaf(wx[2*j+1], wx[2*j+1], fmaf(wy[2*j+1], wy[2*j+1], wz[2*j+1] * wz[2*j+1]));
    wqm[j] = pk2h(-2.0f * wq0, -2.0f * wq1);
  }
  const half2v hone = {(_Float16)1.0f, (_Float16)1.0f};

  // ---- W2^T fragments: 2 n-tiles (cols 32*w + 16*nt + col), 32 VGPRs ----
  half8 w2f[2][4];
#pragma unroll
  for (int nt = 0; nt < 2; nt++) {
    const int n = 32 * w + 16 * nt + col;
#pragma unroll
    for (int ks = 0; ks < 4; ks++) {
      half8 f;
#pragma unroll
      for (int j8 = 0; j8 < 8; j8++)
        f[j8] = (_Float16)W2[(ks * 32 + (quad << 3) + j8) * 128 + n];
      w2f[nt][ks] = f;
    }
  }
  // ---- W3^T fragment, j-permuted to match HG layout (16 VGPRs) ----
  half8 w3f[4];
#pragma unroll
  for (int ks = 0; ks < 4; ks++) {
    half8 f;
#pragma unroll
    for (int j8 = 0; j8 < 8; j8++) {
      int j = 32 * ks + 16 * (j8 & 1) + 4 * quad + (j8 >> 1);
      f[j8] = (_Float16)W3[j * 32 + 16 * nh + col];
    }
    w3f[ks] = f;
  }

  float b2r[2];
#pragma unroll
  for (int nt = 0; nt < 2; nt++) b2r[nt] = b2[32 * w + 16 * nt + col];
  float k2v = 0.0f;
  if (col >= 1) {
    float om = omega[col] * (1.0f / CSND);
    k2v = om * om;
  }
  const float b3v = b3[16 * nh + col];

  float wsum = 0.0f;
  float xrC[3], xrN[3];

  auto loadX = [&](int blk, float* xr) {
    const float* xb = x + (size_t)blk * PB * 3;
    xr[0] = xb[3 * pA]; xr[1] = xb[3 * pA + 1]; xr[2] = xb[3 * pA + 2];
  };

  auto phaseA = [&](int aOff, const float* xr) {
    const int cbase = ((g ^ pA) << 2) + aOff;
    float x0 = xr[0], x1 = xr[1], x2 = xr[2];
    float t[8];
#pragma unroll
    for (int u = 0; u < 8; u++) {
      float z = fmaf(x0, wx[u], fmaf(x1, wy[u], fmaf(x2, wz[u], bB[u])));
      t[u] = mytanh(z);
    }
    half2v tp[4], sp[4];
#pragma unroll
    for (int j = 0; j < 4; j++) {
      tp[j] = pk2h(t[2*j], t[2*j+1]);
      sp[j] = hone - tp[j] * tp[j];
    }
    uint4 q;
    q = make_uint4(U32(tp[0]), U32(tp[1]), U32(tp[2]), U32(tp[3]));
    *(uint4*)&s_mem[(pA)      * 64 + cbase] = q;
    q = make_uint4(U32(sp[0]*wxp[0]), U32(sp[1]*wxp[1]),
                   U32(sp[2]*wxp[2]), U32(sp[3]*wxp[3]));
    *(uint4*)&s_mem[(16 + pA) * 64 + cbase] = q;
    q = make_uint4(U32(sp[0]*wyp[0]), U32(sp[1]*wyp[1]),
                   U32(sp[2]*wyp[2]), U32(sp[3]*wyp[3]));
    *(uint4*)&s_mem[(32 + pA) * 64 + cbase] = q;
    q = make_uint4(U32(sp[0]*wzp[0]), U32(sp[1]*wzp[1]),
                   U32(sp[2]*wzp[2]), U32(sp[3]*wzp[3]));
    *(uint4*)&s_mem[(48 + pA) * 64 + cbase] = q;
    half2v cp[4];
#pragma unroll
    for (int j = 0; j < 4; j++) cp[j] = (tp[j] * sp[j]) * wqm[j];
    q = make_uint4(U32(cp[0]), U32(cp[1]), U32(cp[2]), U32(cp[3]));
    *(uint4*)&s_mem[(64 + pA) * 64 + cbase] = q;
  };

  // standalone D (epilogue only)
  auto phaseD = [&](int hOff) {
    if (w < 2) {
      const int pbase = hOff + col * 128;   // row = col; swizzle key col
      f32x4 dy = (f32x4){0.0f, 0.0f, 0.0f, 0.0f};
      f32x4 dl = (f32x4){0.0f, 0.0f, 0.0f, 0.0f};
#pragma unroll
      for (int ks = 0; ks < 4; ks++) {
        int pos = ((((ks << 2) + quad) ^ col) << 2);
        half8 afy = *(const half8*)&s_mem[pbase + pos];
        half8 afl = *(const half8*)&s_mem[pbase + 64 + pos];
        dy = __builtin_amdgcn_mfma_f32_16x16x32_f16(afy, w3f[ks], dy, 0, 0, 0);
        dl = __builtin_amdgcn_mfma_f32_16x16x32_f16(afl, w3f[ks], dl, 0, 0, 0);
      }
      if (col >= 1) {
#pragma unroll
        for (int r = 0; r < 4; r++) {
          float yv  = dy[r] + b3v;
          float res = fmaf(k2v, yv, dl[r]);
          wsum += res * res;
        }
      }
    }
  };

  // ---- prologue: A(first pass) + x prefetch ----
  loadX(blockIdx.x, xrC);
  phaseA(AOFF(0), xrC);
  {
    int nb = blockIdx.x + GRID;
    if (nb < NBLK) loadX(nb, xrN);
  }
  __syncthreads();

  bool hasPrev = false;
  int cur = 0;
  for (int blk = blockIdx.x; blk < NBLK; blk += GRID) {
    int nblk = blk + GRID;
    // ---- A(i+1) -> bufA[cur^1]  (independent of B/C/D this region) ----
    if (nblk < NBLK) {
      xrC[0] = xrN[0]; xrC[1] = xrN[1]; xrC[2] = xrN[2];
      int n2 = nblk + GRID;
      if (n2 < NBLK) loadX(n2, xrN);
      phaseA(AOFF(cur ^ 1), xrC);
    }

    // ---- B(i) + D(i-1) FUSED: 12 accumulator chains, all 4 waves ----
    const int aOff = AOFF(cur);
    const int pbD  = HOFF(cur ^ 1) + col * 128;  // D's HG row (prev pass)
    f32x4 accd[3][2], acch[2], accc[2];
    f32x4 dy = (f32x4){0.0f, 0.0f, 0.0f, 0.0f};
    f32x4 dl = (f32x4){0.0f, 0.0f, 0.0f, 0.0f};
#pragma unroll
    for (int d = 0; d < 3; d++)
#pragma unroll
      for (int nt = 0; nt < 2; nt++)
        accd[d][nt] = (f32x4){0.0f, 0.0f, 0.0f, 0.0f};
#pragma unroll
    for (int nt = 0; nt < 2; nt++) {
      acch[nt] = (f32x4){0.0f, 0.0f, 0.0f, 0.0f};
      accc[nt] = (f32x4){0.0f, 0.0f, 0.0f, 0.0f};
    }
    {
      const int rbt = aOff + (col) * 64;        // t  rows (v=0)
      const int rb0 = aOff + (16 + col) * 64;   // d0 rows (v=1)
      const int rb1 = aOff + (32 + col) * 64;   // d1 rows (v=2)
      const int rb2 = aOff + (48 + col) * 64;   // d2 rows (v=3)
      const int rbc = aOff + (64 + col) * 64;   // c1 rows (v=4)
#pragma unroll
      for (int ks = 0; ks < 4; ks++) {
        int pos = ((((ks << 2) + quad) ^ col) << 2);
        half8 aft = *(const half8*)&s_mem[rbt + pos];
        half8 af0 = *(const half8*)&s_mem[rb0 + pos];
        half8 af1 = *(const half8*)&s_mem[rb1 + pos];
        half8 af2 = *(const half8*)&s_mem[rb2 + pos];
        half8 afc = *(const half8*)&s_mem[rbc + pos];
        half8 afy = *(const half8*)&s_mem[pbD + pos];
        half8 afl = *(const half8*)&s_mem[pbD + 64 + pos];
        acch[0]    = __builtin_amdgcn_mfma_f32_16x16x32_f16(aft, w2f[0][ks], acch[0],    0, 0, 0);
        acch[1]    = __builtin_amdgcn_mfma_f32_16x16x32_f16(aft, w2f[1][ks], acch[1],    0, 0, 0);
        accd[0][0] = __builtin_amdgcn_mfma_f32_16x16x32_f16(af0, w2f[0][ks], accd[0][0], 0, 0, 0);
        accd[0][1] = __builtin_amdgcn_mfma_f32_16x16x32_f16(af0, w2f[1][ks], accd[0][1], 0, 0, 0);
        accd[1][0] = __builtin_amdgcn_mfma_f32_16x16x32_f16(af1, w2f[0][ks], accd[1][0], 0, 0, 0);
        accd[1][1] = __builtin_amdgcn_mfma_f32_16x16x32_f16(af1, w2f[1][ks], accd[1][1], 0, 0, 0);
        accd[2][0] = __builtin_amdgcn_mfma_f32_16x16x32_f16(af2, w2f[0][ks], accd[2][0], 0, 0, 0);
        accd[2][1] = __builtin_amdgcn_mfma_f32_16x16x32_f16(af2, w2f[1][ks], accd[2][1], 0, 0, 0);
        accc[0]    = __builtin_amdgcn_mfma_f32_16x16x32_f16(afc, w2f[0][ks], accc[0],    0, 0, 0);
        accc[1]    = __builtin_amdgcn_mfma_f32_16x16x32_f16(afc, w2f[1][ks], accc[1],    0, 0, 0);
        dy         = __builtin_amdgcn_mfma_f32_16x16x32_f16(afy, w3f[ks],    dy,         0, 0, 0);
        dl         = __builtin_amdgcn_mfma_f32_16x16x32_f16(afl, w3f[ks],    dl,         0, 0, 0);
      }
    }
    // D residual: discard duplicates (waves 2/3) and first pass (garbage HG)
    if (hasPrev && w < 2 && col >= 1) {
#pragma unroll
      for (int r = 0; r < 4; r++) {
        float yv  = dy[r] + b3v;
        float res = fmaf(k2v, yv, dl[r]);
        wsum += res * res;
      }
    }
    f32x4 bsum[2];
#pragma unroll
    for (int nt = 0; nt < 2; nt++)
      bsum[nt] = accd[0][nt] * accd[0][nt] + accd[1][nt] * accd[1][nt]
               + accd[2][nt] * accd[2][nt];

    // ---- C(i): layer-2 elementwise -> bufHG[cur] (q = 16w+col) ----
    {
      const int hOff = HOFF(cur);
      const int q    = 16 * w + col;
      const int qc   = q >> 2, qr = q & 3;
#pragma unroll
      for (int r = 0; r < 4; r++) {
        int p = (quad << 2) + r;             // point 0..15
        float t2[2], gg[2];
#pragma unroll
        for (int nt = 0; nt < 2; nt++) {
          float z2 = acch[nt][r] + b2r[nt];
          float t  = mytanh(z2);
          float s2 = 1.0f - t * t;
          t2[nt] = t;
          gg[nt] = s2 * (accc[nt][r] - 2.0f * t * bsum[nt][r]);
        }
        int pos = ((qc ^ p) << 2) + qr;
        int pb  = hOff + p * 128;
        s_mem[pb + pos]      = pack2(t2[0], t2[1]);
        s_mem[pb + 64 + pos] = pack2(gg[0], gg[1]);
      }
    }

    hasPrev = true;
    __syncthreads();               // single barrier per pass
    cur ^= 1;
  }
  phaseD(HOFF(cur ^ 1));           // epilogue D (last C wrote bufHG[cur^1])

  // ---- final: wave reduce, one atomic per wave ----
#pragma unroll
  for (int off = 32; off > 0; off >>= 1)
    wsum += __shfl_down(wsum, off, 64);
  if (l == 0)
    atomicAdd(out, wsum * (1.0f / ((float)NPTS * (float)(FCH - 1))));
}

extern "C" void kernel_launch(void* const* d_in, const int* in_sizes, int n_in,
                              void* d_out, int out_size, void* d_ws, size_t ws_size,
                              hipStream_t stream) {
  const float* x     = (const float*)d_in[0];
  const float* omega = (const float*)d_in[1];
  const float* W1    = (const float*)d_in[2];
  const float* b1    = (const float*)d_in[3];
  const float* W2    = (const float*)d_in[4];
  const float* b2    = (const float*)d_in[5];
  const float* W3    = (const float*)d_in[6];
  const float* b3    = (const float*)d_in[7];
  float* out = (float*)d_out;

  (void)hipMemsetAsync(out, 0, sizeof(float), stream);
  helmholtz_kernel<<<GRID, BLOCK, 0, stream>>>(x, omega, W1, b1, W2, b2, W3, b3, out);
}

// Round 24
// 116.998 us; speedup vs baseline: 1.0272x; 1.0016x over previous
//
#include <hip/hip_runtime.h>
#include <math.h>

#ifndef __has_builtin
#define __has_builtin(x) 0
#endif

#define NPTS   131072
#define FCH    16
#define CSND   343.0f
#define PB     16           // points per pass
#define BLOCK  256          // 4 waves
#define GRID   512          // 2 WG/CU * 256 CUs, persistent (16 passes/WG)
#define NBLK   (NPTS / PB)  // 8192

// LDS dword offsets (total 14336 dw = 56 KB -> 2 WG/CU):
//   bufA[k]  = k*5120        (80 rows x 64 dw, k=0/1)
//   bufHG[k] = 10240 + k*2048 (16 x 128 dw,    k=0/1)
#define AOFF(k)  ((k) * 5120)
#define HOFF(k)  (10240 + (k) * 2048)

typedef _Float16 half8 __attribute__((ext_vector_type(8)));
typedef _Float16 half2v __attribute__((ext_vector_type(2)));
typedef float    f32x4 __attribute__((ext_vector_type(4)));

static __device__ __forceinline__ half2v pk2h(float a, float b) {
#if __has_builtin(__builtin_amdgcn_cvt_pkrtz)
  return __builtin_bit_cast(half2v, __builtin_amdgcn_cvt_pkrtz(a, b));
#else
  half2v v; v[0] = (_Float16)a; v[1] = (_Float16)b;
  return v;
#endif
}
static __device__ __forceinline__ unsigned pack2(float a, float b) {
  return __builtin_bit_cast(unsigned, pk2h(a, b));
}
#define U32(h) __builtin_bit_cast(unsigned, (h))

// tanh(x) = 1 - 2/(e^{2x}+1): exp+rcp on trans pipe, monotone at +/-inf.
static __device__ __forceinline__ float mytanh(float x) {
#if __has_builtin(__builtin_amdgcn_exp2f)
  float e = __builtin_amdgcn_exp2f(2.885390082f * x);   // 2*log2(e)*x
#else
  float e = __expf(2.0f * x);
#endif
  return fmaf(-2.0f, __builtin_amdgcn_rcpf(e + 1.0f), 1.0f);
}

// FINAL KERNEL == R18 (quadruple-sampled: R18/R21/R22 direct, R23 fused
// variant within noise). Steady dispatches 54.9-56.5us, bench 117.4-119.1us,
// VGPR=108, zero spills. Session arc: 72us (R0) -> 59.4 (R6 packed-f16 A +
// stagger) -> 56.5 (R9 1-barrier pipelined dbuf) -> 55.1 (R18 10-chain
// merged B, no setprio). R23's D-fusion (all-wave, in-ks-loop) was null:
// MfmaUtil 16->17.3 as predicted but no time gain -> reverted.
// Declared constraint (NOT a pipe roofline -- MfmaUtil 16%, VALUBusy 30%,
// HBM 0.35%): dependency-latency plateau of this phase-chain at HIP source
// level (~8.3k cyc/pass elapsed vs ~1.3k issue). Measured-and-exhausted:
// occupancy (anti-correlated 14-35%, 5 configs), barrier-event halving
// (slower), LDS traffic -40% (slower), WG shapes (slower), setprio
// (-3.5us), register pipelining (null), D-fusion (null), spill regimes x4
// (fatal). Remaining headroom requires an inline-asm counted-waitcnt loop
// (AITER-style full rewrite).
// Structure: 1-barrier pipelined pass, dbuf parity:
//   [A(i+1)->bufA[!c] || D(i-1) rd HG[!c] || B(i) 10-chain; C(i)->HG[c]] |bar|
// B: ONE ks-loop, 10 independent MFMA chains (t x2, d0/d1/d2 x2, c1 x2),
// all 5 ds_read streams issued per ks. Hazards parity-ordered across the
// single barrier. Phases: A packed-f16 (1pt/thread); C q=16w+col; D waves
// 0/1 (w3f j-perm j = 32ks+16(j8&1)+4quad+(j8>>1)).

__global__ __launch_bounds__(BLOCK, 2) void helmholtz_kernel(
    const float* __restrict__ x,      // [N,3]
    const float* __restrict__ omega,  // [16]
    const float* __restrict__ W1,     // [3,128]
    const float* __restrict__ b1,     // [128]
    const float* __restrict__ W2,     // [128,128]
    const float* __restrict__ b2,     // [128]
    const float* __restrict__ W3,     // [128,32]
    const float* __restrict__ b3,     // [32]
    float* __restrict__ out)
{
  __shared__ unsigned s_mem[14336];   // 56 KB: 2x bufA + 2x bufHG

  // ---- one-time half-pass stagger: de-convoy the 2 WGs sharing each CU ----
  if ((blockIdx.x >> 8) & 1) {
#pragma unroll
    for (int i = 0; i < 3; i++) __builtin_amdgcn_s_sleep(48);
  }

  const int tid  = threadIdx.x;
  const int w    = tid >> 6;   // wave 0..3
  const int l    = tid & 63;
  const int col  = l & 15;
  const int quad = l >> 4;
  const int nh   = w & 1;      // D re/im tile (waves 0/1)

  // ---- phase A task: point pA (one per thread); units 8g..8g+7 ----
  const int pA = tid >> 4;     // 0..15
  const int g  = tid & 15;
  float wx[8], wy[8], wz[8], bB[8];
#pragma unroll
  for (int u = 0; u < 8; u++) {
    int unit = 8 * g + u;
    wx[u] = W1[unit]; wy[u] = W1[128 + unit]; wz[u] = W1[256 + unit];
    bB[u] = b1[unit];
  }
  // packed W1 copies + folded -2*wq (computed once)
  half2v wxp[4], wyp[4], wzp[4], wqm[4];
#pragma unroll
  for (int j = 0; j < 4; j++) {
    wxp[j] = pk2h(wx[2*j], wx[2*j+1]);
    wyp[j] = pk2h(wy[2*j], wy[2*j+1]);
    wzp[j] = pk2h(wz[2*j], wz[2*j+1]);
    float wq0 = fmaf(wx[2*j],   wx[2*j],   fmaf(wy[2*j],   wy[2*j],   wz[2*j]   * wz[2*j]));
    float wq1 = fmaf(wx[2*j+1], wx[2*j+1], fmaf(wy[2*j+1], wy[2*j+1], wz[2*j+1] * wz[2*j+1]));
    wqm[j] = pk2h(-2.0f * wq0, -2.0f * wq1);
  }
  const half2v hone = {(_Float16)1.0f, (_Float16)1.0f};

  // ---- W2^T fragments: 2 n-tiles (cols 32*w + 16*nt + col), 32 VGPRs ----
  half8 w2f[2][4];
#pragma unroll
  for (int nt = 0; nt < 2; nt++) {
    const int n = 32 * w + 16 * nt + col;
#pragma unroll
    for (int ks = 0; ks < 4; ks++) {
      half8 f;
#pragma unroll
      for (int j8 = 0; j8 < 8; j8++)
        f[j8] = (_Float16)W2[(ks * 32 + (quad << 3) + j8) * 128 + n];
      w2f[nt][ks] = f;
    }
  }
  // ---- W3^T fragment, j-permuted to match HG layout (16 VGPRs) ----
  half8 w3f[4];
#pragma unroll
  for (int ks = 0; ks < 4; ks++) {
    half8 f;
#pragma unroll
    for (int j8 = 0; j8 < 8; j8++) {
      int j = 32 * ks + 16 * (j8 & 1) + 4 * quad + (j8 >> 1);
      f[j8] = (_Float16)W3[j * 32 + 16 * nh + col];
    }
    w3f[ks] = f;
  }

  float b2r[2];
#pragma unroll
  for (int nt = 0; nt < 2; nt++) b2r[nt] = b2[32 * w + 16 * nt + col];
  float k2v = 0.0f;
  if (col >= 1) {
    float om = omega[col] * (1.0f / CSND);
    k2v = om * om;
  }
  const float b3v = b3[16 * nh + col];

  float wsum = 0.0f;
  float xrC[3], xrN[3];

  auto loadX = [&](int blk, float* xr) {
    const float* xb = x + (size_t)blk * PB * 3;
    xr[0] = xb[3 * pA]; xr[1] = xb[3 * pA + 1]; xr[2] = xb[3 * pA + 2];
  };

  auto phaseA = [&](int aOff, const float* xr) {
    const int cbase = ((g ^ pA) << 2) + aOff;
    float x0 = xr[0], x1 = xr[1], x2 = xr[2];
    float t[8];
#pragma unroll
    for (int u = 0; u < 8; u++) {
      float z = fmaf(x0, wx[u], fmaf(x1, wy[u], fmaf(x2, wz[u], bB[u])));
      t[u] = mytanh(z);
    }
    half2v tp[4], sp[4];
#pragma unroll
    for (int j = 0; j < 4; j++) {
      tp[j] = pk2h(t[2*j], t[2*j+1]);
      sp[j] = hone - tp[j] * tp[j];
    }
    uint4 q;
    q = make_uint4(U32(tp[0]), U32(tp[1]), U32(tp[2]), U32(tp[3]));
    *(uint4*)&s_mem[(pA)      * 64 + cbase] = q;
    q = make_uint4(U32(sp[0]*wxp[0]), U32(sp[1]*wxp[1]),
                   U32(sp[2]*wxp[2]), U32(sp[3]*wxp[3]));
    *(uint4*)&s_mem[(16 + pA) * 64 + cbase] = q;
    q = make_uint4(U32(sp[0]*wyp[0]), U32(sp[1]*wyp[1]),
                   U32(sp[2]*wyp[2]), U32(sp[3]*wyp[3]));
    *(uint4*)&s_mem[(32 + pA) * 64 + cbase] = q;
    q = make_uint4(U32(sp[0]*wzp[0]), U32(sp[1]*wzp[1]),
                   U32(sp[2]*wzp[2]), U32(sp[3]*wzp[3]));
    *(uint4*)&s_mem[(48 + pA) * 64 + cbase] = q;
    half2v cp[4];
#pragma unroll
    for (int j = 0; j < 4; j++) cp[j] = (tp[j] * sp[j]) * wqm[j];
    q = make_uint4(U32(cp[0]), U32(cp[1]), U32(cp[2]), U32(cp[3]));
    *(uint4*)&s_mem[(64 + pA) * 64 + cbase] = q;
  };

  auto phaseD = [&](int hOff) {
    if (w < 2) {
      const int pbase = hOff + col * 128;   // row = col; swizzle key col
      f32x4 dy = (f32x4){0.0f, 0.0f, 0.0f, 0.0f};
      f32x4 dl = (f32x4){0.0f, 0.0f, 0.0f, 0.0f};
#pragma unroll
      for (int ks = 0; ks < 4; ks++) {
        int pos = ((((ks << 2) + quad) ^ col) << 2);
        half8 afy = *(const half8*)&s_mem[pbase + pos];
        half8 afl = *(const half8*)&s_mem[pbase + 64 + pos];
        dy = __builtin_amdgcn_mfma_f32_16x16x32_f16(afy, w3f[ks], dy, 0, 0, 0);
        dl = __builtin_amdgcn_mfma_f32_16x16x32_f16(afl, w3f[ks], dl, 0, 0, 0);
      }
      if (col >= 1) {
#pragma unroll
        for (int r = 0; r < 4; r++) {
          float yv  = dy[r] + b3v;
          float res = fmaf(k2v, yv, dl[r]);
          wsum += res * res;
        }
      }
    }
  };

  // ---- prologue: A(first pass) + x prefetch ----
  loadX(blockIdx.x, xrC);
  phaseA(AOFF(0), xrC);
  {
    int nb = blockIdx.x + GRID;
    if (nb < NBLK) loadX(nb, xrN);
  }
  __syncthreads();

  bool hasPrev = false;
  int cur = 0;
  for (int blk = blockIdx.x; blk < NBLK; blk += GRID) {
    int nblk = blk + GRID;
    // ---- A(i+1) -> bufA[cur^1]  (independent of B/C/D this region) ----
    if (nblk < NBLK) {
      xrC[0] = xrN[0]; xrC[1] = xrN[1]; xrC[2] = xrN[2];
      int n2 = nblk + GRID;
      if (n2 < NBLK) loadX(n2, xrN);
      phaseA(AOFF(cur ^ 1), xrC);
    }
    // ---- D(i-1): reads bufHG[cur^1]  (independent) ----
    if (hasPrev) phaseD(HOFF(cur ^ 1));

    // ---- B(i): MERGED GEMM, 10 independent accumulator chains ----
    const int aOff = AOFF(cur);
    f32x4 accd[3][2], acch[2], accc[2];
#pragma unroll
    for (int d = 0; d < 3; d++)
#pragma unroll
      for (int nt = 0; nt < 2; nt++)
        accd[d][nt] = (f32x4){0.0f, 0.0f, 0.0f, 0.0f};
#pragma unroll
    for (int nt = 0; nt < 2; nt++) {
      acch[nt] = (f32x4){0.0f, 0.0f, 0.0f, 0.0f};
      accc[nt] = (f32x4){0.0f, 0.0f, 0.0f, 0.0f};
    }
    {
      const int rbt = aOff + (col) * 64;        // t  rows (v=0)
      const int rb0 = aOff + (16 + col) * 64;   // d0 rows (v=1)
      const int rb1 = aOff + (32 + col) * 64;   // d1 rows (v=2)
      const int rb2 = aOff + (48 + col) * 64;   // d2 rows (v=3)
      const int rbc = aOff + (64 + col) * 64;   // c1 rows (v=4)
#pragma unroll
      for (int ks = 0; ks < 4; ks++) {
        int pos = ((((ks << 2) + quad) ^ col) << 2);
        half8 aft = *(const half8*)&s_mem[rbt + pos];
        half8 af0 = *(const half8*)&s_mem[rb0 + pos];
        half8 af1 = *(const half8*)&s_mem[rb1 + pos];
        half8 af2 = *(const half8*)&s_mem[rb2 + pos];
        half8 afc = *(const half8*)&s_mem[rbc + pos];
        acch[0]    = __builtin_amdgcn_mfma_f32_16x16x32_f16(aft, w2f[0][ks], acch[0],    0, 0, 0);
        acch[1]    = __builtin_amdgcn_mfma_f32_16x16x32_f16(aft, w2f[1][ks], acch[1],    0, 0, 0);
        accd[0][0] = __builtin_amdgcn_mfma_f32_16x16x32_f16(af0, w2f[0][ks], accd[0][0], 0, 0, 0);
        accd[0][1] = __builtin_amdgcn_mfma_f32_16x16x32_f16(af0, w2f[1][ks], accd[0][1], 0, 0, 0);
        accd[1][0] = __builtin_amdgcn_mfma_f32_16x16x32_f16(af1, w2f[0][ks], accd[1][0], 0, 0, 0);
        accd[1][1] = __builtin_amdgcn_mfma_f32_16x16x32_f16(af1, w2f[1][ks], accd[1][1], 0, 0, 0);
        accd[2][0] = __builtin_amdgcn_mfma_f32_16x16x32_f16(af2, w2f[0][ks], accd[2][0], 0, 0, 0);
        accd[2][1] = __builtin_amdgcn_mfma_f32_16x16x32_f16(af2, w2f[1][ks], accd[2][1], 0, 0, 0);
        accc[0]    = __builtin_amdgcn_mfma_f32_16x16x32_f16(afc, w2f[0][ks], accc[0],    0, 0, 0);
        accc[1]    = __builtin_amdgcn_mfma_f32_16x16x32_f16(afc, w2f[1][ks], accc[1],    0, 0, 0);
      }
    }
    f32x4 bsum[2];
#pragma unroll
    for (int nt = 0; nt < 2; nt++)
      bsum[nt] = accd[0][nt] * accd[0][nt] + accd[1][nt] * accd[1][nt]
               + accd[2][nt] * accd[2][nt];

    // ---- C(i): layer-2 elementwise -> bufHG[cur] (q = 16w+col) ----
    {
      const int hOff = HOFF(cur);
      const int q    = 16 * w + col;
      const int qc   = q >> 2, qr = q & 3;
#pragma unroll
      for (int r = 0; r < 4; r++) {
        int p = (quad << 2) + r;             // point 0..15
        float t2[2], gg[2];
#pragma unroll
        for (int nt = 0; nt < 2; nt++) {
          float z2 = acch[nt][r] + b2r[nt];
          float t  = mytanh(z2);
          float s2 = 1.0f - t * t;
          t2[nt] = t;
          gg[nt] = s2 * (accc[nt][r] - 2.0f * t * bsum[nt][r]);
        }
        int pos = ((qc ^ p) << 2) + qr;
        int pb  = hOff + p * 128;
        s_mem[pb + pos]      = pack2(t2[0], t2[1]);
        s_mem[pb + 64 + pos] = pack2(gg[0], gg[1]);
      }
    }

    hasPrev = true;
    __syncthreads();               // single barrier per pass
    cur ^= 1;
  }
  phaseD(HOFF(cur ^ 1));           // epilogue D (last C wrote bufHG[cur^1])

  // ---- final: wave reduce, one atomic per wave ----
#pragma unroll
  for (int off = 32; off > 0; off >>= 1)
    wsum += __shfl_down(wsum, off, 64);
  if (l == 0)
    atomicAdd(out, wsum * (1.0f / ((float)NPTS * (float)(FCH - 1))));
}

extern "C" void kernel_launch(void* const* d_in, const int* in_sizes, int n_in,
                              void* d_out, int out_size, void* d_ws, size_t ws_size,
                              hipStream_t stream) {
  const float* x     = (const float*)d_in[0];
  const float* omega = (const float*)d_in[1];
  const float* W1    = (const float*)d_in[2];
  const float* b1    = (const float*)d_in[3];
  const float* W2    = (const float*)d_in[4];
  const float* b2    = (const float*)d_in[5];
  const float* W3    = (const float*)d_in[6];
  const float* b3    = (const float*)d_in[7];
  float* out = (float*)d_out;

  (void)hipMemsetAsync(out, 0, sizeof(float), stream);
  helmholtz_kernel<<<GRID, BLOCK, 0, stream>>>(x, omega, W1, b1, W2, b2, W3, b3, out);
}

// Round 25
// 116.497 us; speedup vs baseline: 1.0316x; 1.0043x over previous
//
#include <hip/hip_runtime.h>
#include <math.h>

#ifndef __has_builtin
#define __has_builtin(x) 0
#endif

#define NPTS   131072
#define FCH    16
#define CSND   343.0f
#define PB     16           // points per pass
#define BLOCK  256          // 4 waves
#define GRID   512          // 2 WG/CU * 256 CUs, persistent (16 passes/WG)
#define NBLK   (NPTS / PB)  // 8192

// LDS dword offsets (total 14336 dw = 56 KB -> 2 WG/CU):
//   bufA[k]  = k*5120        (80 rows x 64 dw, k=0/1)
//   bufHG[k] = 10240 + k*2048 (16 x 128 dw,    k=0/1)
#define AOFF(k)  ((k) * 5120)
#define HOFF(k)  (10240 + (k) * 2048)

typedef _Float16 half8 __attribute__((ext_vector_type(8)));
typedef _Float16 half2v __attribute__((ext_vector_type(2)));
typedef float    f32x4 __attribute__((ext_vector_type(4)));

static __device__ __forceinline__ half2v pk2h(float a, float b) {
#if __has_builtin(__builtin_amdgcn_cvt_pkrtz)
  return __builtin_bit_cast(half2v, __builtin_amdgcn_cvt_pkrtz(a, b));
#else
  half2v v; v[0] = (_Float16)a; v[1] = (_Float16)b;
  return v;
#endif
}
static __device__ __forceinline__ unsigned pack2(float a, float b) {
  return __builtin_bit_cast(unsigned, pk2h(a, b));
}
#define U32(h) __builtin_bit_cast(unsigned, (h))

// tanh(x) = 1 - 2/(e^{2x}+1): exp+rcp on trans pipe, monotone at +/-inf.
static __device__ __forceinline__ float mytanh(float x) {
#if __has_builtin(__builtin_amdgcn_exp2f)
  float e = __builtin_amdgcn_exp2f(2.885390082f * x);   // 2*log2(e)*x
#else
  float e = __expf(2.0f * x);
#endif
  return fmaf(-2.0f, __builtin_amdgcn_rcpf(e + 1.0f), 1.0f);
}

// FINAL KERNEL == R18, five-sampled (R18/R21/R22/R24 direct; R23 variant
// within noise): dispatches 54.9-57.2us, bench 117.0-119.1us, VGPR=108,
// zero spills. Session arc: 72us (R0) -> 59.4 (R6 packed-f16 A + stagger)
// -> 56.5 (R9 1-barrier pipelined dbuf) -> ~55 (R18 10-chain merged B).
// Declared constraint (NOT a pipe roofline -- MfmaUtil 16%, VALUBusy 30%,
// HBM 0.35%): dependency-latency plateau of this phase-chain at HIP source
// level (~8.3k cyc/pass elapsed vs ~1.3k issue; pipe floors LDS ~20us /
// VALU ~16us / MFMA ~8.5us all << 55us). Measured-and-exhausted levers:
// occupancy (anti-correlated, 5 configs), barrier-event halving (slower),
// LDS traffic -40% (slower), WG shapes (slower), setprio (-3.5us),
// register pipelining (null), D-fusion (null), spill regimes x4 (fatal).
// Remaining headroom requires an inline-asm counted-waitcnt loop
// (AITER-style full rewrite; guide m131-m141: not expressible from source).
// Structure: 1-barrier pipelined pass, dbuf parity:
//   [A(i+1)->bufA[!c] || D(i-1) rd HG[!c] || B(i) 10-chain; C(i)->HG[c]] |bar|
// B: ONE ks-loop, 10 independent MFMA chains (t x2, d0/d1/d2 x2, c1 x2),
// all 5 ds_read streams issued per ks. Hazards parity-ordered across the
// single barrier. Phases: A packed-f16 (1pt/thread); C q=16w+col; D waves
// 0/1 (w3f j-perm j = 32ks+16(j8&1)+4quad+(j8>>1)).

__global__ __launch_bounds__(BLOCK, 2) void helmholtz_kernel(
    const float* __restrict__ x,      // [N,3]
    const float* __restrict__ omega,  // [16]
    const float* __restrict__ W1,     // [3,128]
    const float* __restrict__ b1,     // [128]
    const float* __restrict__ W2,     // [128,128]
    const float* __restrict__ b2,     // [128]
    const float* __restrict__ W3,     // [128,32]
    const float* __restrict__ b3,     // [32]
    float* __restrict__ out)
{
  __shared__ unsigned s_mem[14336];   // 56 KB: 2x bufA + 2x bufHG

  // ---- one-time half-pass stagger: de-convoy the 2 WGs sharing each CU ----
  if ((blockIdx.x >> 8) & 1) {
#pragma unroll
    for (int i = 0; i < 3; i++) __builtin_amdgcn_s_sleep(48);
  }

  const int tid  = threadIdx.x;
  const int w    = tid >> 6;   // wave 0..3
  const int l    = tid & 63;
  const int col  = l & 15;
  const int quad = l >> 4;
  const int nh   = w & 1;      // D re/im tile (waves 0/1)

  // ---- phase A task: point pA (one per thread); units 8g..8g+7 ----
  const int pA = tid >> 4;     // 0..15
  const int g  = tid & 15;
  float wx[8], wy[8], wz[8], bB[8];
#pragma unroll
  for (int u = 0; u < 8; u++) {
    int unit = 8 * g + u;
    wx[u] = W1[unit]; wy[u] = W1[128 + unit]; wz[u] = W1[256 + unit];
    bB[u] = b1[unit];
  }
  // packed W1 copies + folded -2*wq (computed once)
  half2v wxp[4], wyp[4], wzp[4], wqm[4];
#pragma unroll
  for (int j = 0; j < 4; j++) {
    wxp[j] = pk2h(wx[2*j], wx[2*j+1]);
    wyp[j] = pk2h(wy[2*j], wy[2*j+1]);
    wzp[j] = pk2h(wz[2*j], wz[2*j+1]);
    float wq0 = fmaf(wx[2*j],   wx[2*j],   fmaf(wy[2*j],   wy[2*j],   wz[2*j]   * wz[2*j]));
    float wq1 = fmaf(wx[2*j+1], wx[2*j+1], fmaf(wy[2*j+1], wy[2*j+1], wz[2*j+1] * wz[2*j+1]));
    wqm[j] = pk2h(-2.0f * wq0, -2.0f * wq1);
  }
  const half2v hone = {(_Float16)1.0f, (_Float16)1.0f};

  // ---- W2^T fragments: 2 n-tiles (cols 32*w + 16*nt + col), 32 VGPRs ----
  half8 w2f[2][4];
#pragma unroll
  for (int nt = 0; nt < 2; nt++) {
    const int n = 32 * w + 16 * nt + col;
#pragma unroll
    for (int ks = 0; ks < 4; ks++) {
      half8 f;
#pragma unroll
      for (int j8 = 0; j8 < 8; j8++)
        f[j8] = (_Float16)W2[(ks * 32 + (quad << 3) + j8) * 128 + n];
      w2f[nt][ks] = f;
    }
  }
  // ---- W3^T fragment, j-permuted to match HG layout (16 VGPRs) ----
  half8 w3f[4];
#pragma unroll
  for (int ks = 0; ks < 4; ks++) {
    half8 f;
#pragma unroll
    for (int j8 = 0; j8 < 8; j8++) {
      int j = 32 * ks + 16 * (j8 & 1) + 4 * quad + (j8 >> 1);
      f[j8] = (_Float16)W3[j * 32 + 16 * nh + col];
    }
    w3f[ks] = f;
  }

  float b2r[2];
#pragma unroll
  for (int nt = 0; nt < 2; nt++) b2r[nt] = b2[32 * w + 16 * nt + col];
  float k2v = 0.0f;
  if (col >= 1) {
    float om = omega[col] * (1.0f / CSND);
    k2v = om * om;
  }
  const float b3v = b3[16 * nh + col];

  float wsum = 0.0f;
  float xrC[3], xrN[3];

  auto loadX = [&](int blk, float* xr) {
    const float* xb = x + (size_t)blk * PB * 3;
    xr[0] = xb[3 * pA]; xr[1] = xb[3 * pA + 1]; xr[2] = xb[3 * pA + 2];
  };

  auto phaseA = [&](int aOff, const float* xr) {
    const int cbase = ((g ^ pA) << 2) + aOff;
    float x0 = xr[0], x1 = xr[1], x2 = xr[2];
    float t[8];
#pragma unroll
    for (int u = 0; u < 8; u++) {
      float z = fmaf(x0, wx[u], fmaf(x1, wy[u], fmaf(x2, wz[u], bB[u])));
      t[u] = mytanh(z);
    }
    half2v tp[4], sp[4];
#pragma unroll
    for (int j = 0; j < 4; j++) {
      tp[j] = pk2h(t[2*j], t[2*j+1]);
      sp[j] = hone - tp[j] * tp[j];
    }
    uint4 q;
    q = make_uint4(U32(tp[0]), U32(tp[1]), U32(tp[2]), U32(tp[3]));
    *(uint4*)&s_mem[(pA)      * 64 + cbase] = q;
    q = make_uint4(U32(sp[0]*wxp[0]), U32(sp[1]*wxp[1]),
                   U32(sp[2]*wxp[2]), U32(sp[3]*wxp[3]));
    *(uint4*)&s_mem[(16 + pA) * 64 + cbase] = q;
    q = make_uint4(U32(sp[0]*wyp[0]), U32(sp[1]*wyp[1]),
                   U32(sp[2]*wyp[2]), U32(sp[3]*wyp[3]));
    *(uint4*)&s_mem[(32 + pA) * 64 + cbase] = q;
    q = make_uint4(U32(sp[0]*wzp[0]), U32(sp[1]*wzp[1]),
                   U32(sp[2]*wzp[2]), U32(sp[3]*wzp[3]));
    *(uint4*)&s_mem[(48 + pA) * 64 + cbase] = q;
    half2v cp[4];
#pragma unroll
    for (int j = 0; j < 4; j++) cp[j] = (tp[j] * sp[j]) * wqm[j];
    q = make_uint4(U32(cp[0]), U32(cp[1]), U32(cp[2]), U32(cp[3]));
    *(uint4*)&s_mem[(64 + pA) * 64 + cbase] = q;
  };

  auto phaseD = [&](int hOff) {
    if (w < 2) {
      const int pbase = hOff + col * 128;   // row = col; swizzle key col
      f32x4 dy = (f32x4){0.0f, 0.0f, 0.0f, 0.0f};
      f32x4 dl = (f32x4){0.0f, 0.0f, 0.0f, 0.0f};
#pragma unroll
      for (int ks = 0; ks < 4; ks++) {
        int pos = ((((ks << 2) + quad) ^ col) << 2);
        half8 afy = *(const half8*)&s_mem[pbase + pos];
        half8 afl = *(const half8*)&s_mem[pbase + 64 + pos];
        dy = __builtin_amdgcn_mfma_f32_16x16x32_f16(afy, w3f[ks], dy, 0, 0, 0);
        dl = __builtin_amdgcn_mfma_f32_16x16x32_f16(afl, w3f[ks], dl, 0, 0, 0);
      }
      if (col >= 1) {
#pragma unroll
        for (int r = 0; r < 4; r++) {
          float yv  = dy[r] + b3v;
          float res = fmaf(k2v, yv, dl[r]);
          wsum += res * res;
        }
      }
    }
  };

  // ---- prologue: A(first pass) + x prefetch ----
  loadX(blockIdx.x, xrC);
  phaseA(AOFF(0), xrC);
  {
    int nb = blockIdx.x + GRID;
    if (nb < NBLK) loadX(nb, xrN);
  }
  __syncthreads();

  bool hasPrev = false;
  int cur = 0;
  for (int blk = blockIdx.x; blk < NBLK; blk += GRID) {
    int nblk = blk + GRID;
    // ---- A(i+1) -> bufA[cur^1]  (independent of B/C/D this region) ----
    if (nblk < NBLK) {
      xrC[0] = xrN[0]; xrC[1] = xrN[1]; xrC[2] = xrN[2];
      int n2 = nblk + GRID;
      if (n2 < NBLK) loadX(n2, xrN);
      phaseA(AOFF(cur ^ 1), xrC);
    }
    // ---- D(i-1): reads bufHG[cur^1]  (independent) ----
    if (hasPrev) phaseD(HOFF(cur ^ 1));

    // ---- B(i): MERGED GEMM, 10 independent accumulator chains ----
    const int aOff = AOFF(cur);
    f32x4 accd[3][2], acch[2], accc[2];
#pragma unroll
    for (int d = 0; d < 3; d++)
#pragma unroll
      for (int nt = 0; nt < 2; nt++)
        accd[d][nt] = (f32x4){0.0f, 0.0f, 0.0f, 0.0f};
#pragma unroll
    for (int nt = 0; nt < 2; nt++) {
      acch[nt] = (f32x4){0.0f, 0.0f, 0.0f, 0.0f};
      accc[nt] = (f32x4){0.0f, 0.0f, 0.0f, 0.0f};
    }
    {
      const int rbt = aOff + (col) * 64;        // t  rows (v=0)
      const int rb0 = aOff + (16 + col) * 64;   // d0 rows (v=1)
      const int rb1 = aOff + (32 + col) * 64;   // d1 rows (v=2)
      const int rb2 = aOff + (48 + col) * 64;   // d2 rows (v=3)
      const int rbc = aOff + (64 + col) * 64;   // c1 rows (v=4)
#pragma unroll
      for (int ks = 0; ks < 4; ks++) {
        int pos = ((((ks << 2) + quad) ^ col) << 2);
        half8 aft = *(const half8*)&s_mem[rbt + pos];
        half8 af0 = *(const half8*)&s_mem[rb0 + pos];
        half8 af1 = *(const half8*)&s_mem[rb1 + pos];
        half8 af2 = *(const half8*)&s_mem[rb2 + pos];
        half8 afc = *(const half8*)&s_mem[rbc + pos];
        acch[0]    = __builtin_amdgcn_mfma_f32_16x16x32_f16(aft, w2f[0][ks], acch[0],    0, 0, 0);
        acch[1]    = __builtin_amdgcn_mfma_f32_16x16x32_f16(aft, w2f[1][ks], acch[1],    0, 0, 0);
        accd[0][0] = __builtin_amdgcn_mfma_f32_16x16x32_f16(af0, w2f[0][ks], accd[0][0], 0, 0, 0);
        accd[0][1] = __builtin_amdgcn_mfma_f32_16x16x32_f16(af0, w2f[1][ks], accd[0][1], 0, 0, 0);
        accd[1][0] = __builtin_amdgcn_mfma_f32_16x16x32_f16(af1, w2f[0][ks], accd[1][0], 0, 0, 0);
        accd[1][1] = __builtin_amdgcn_mfma_f32_16x16x32_f16(af1, w2f[1][ks], accd[1][1], 0, 0, 0);
        accd[2][0] = __builtin_amdgcn_mfma_f32_16x16x32_f16(af2, w2f[0][ks], accd[2][0], 0, 0, 0);
        accd[2][1] = __builtin_amdgcn_mfma_f32_16x16x32_f16(af2, w2f[1][ks], accd[2][1], 0, 0, 0);
        accc[0]    = __builtin_amdgcn_mfma_f32_16x16x32_f16(afc, w2f[0][ks], accc[0],    0, 0, 0);
        accc[1]    = __builtin_amdgcn_mfma_f32_16x16x32_f16(afc, w2f[1][ks], accc[1],    0, 0, 0);
      }
    }
    f32x4 bsum[2];
#pragma unroll
    for (int nt = 0; nt < 2; nt++)
      bsum[nt] = accd[0][nt] * accd[0][nt] + accd[1][nt] * accd[1][nt]
               + accd[2][nt] * accd[2][nt];

    // ---- C(i): layer-2 elementwise -> bufHG[cur] (q = 16w+col) ----
    {
      const int hOff = HOFF(cur);
      const int q    = 16 * w + col;
      const int qc   = q >> 2, qr = q & 3;
#pragma unroll
      for (int r = 0; r < 4; r++) {
        int p = (quad << 2) + r;             // point 0..15
        float t2[2], gg[2];
#pragma unroll
        for (int nt = 0; nt < 2; nt++) {
          float z2 = acch[nt][r] + b2r[nt];
          float t  = mytanh(z2);
          float s2 = 1.0f - t * t;
          t2[nt] = t;
          gg[nt] = s2 * (accc[nt][r] - 2.0f * t * bsum[nt][r]);
        }
        int pos = ((qc ^ p) << 2) + qr;
        int pb  = hOff + p * 128;
        s_mem[pb + pos]      = pack2(t2[0], t2[1]);
        s_mem[pb + 64 + pos] = pack2(gg[0], gg[1]);
      }
    }

    hasPrev = true;
    __syncthreads();               // single barrier per pass
    cur ^= 1;
  }
  phaseD(HOFF(cur ^ 1));           // epilogue D (last C wrote bufHG[cur^1])

  // ---- final: wave reduce, one atomic per wave ----
#pragma unroll
  for (int off = 32; off > 0; off >>= 1)
    wsum += __shfl_down(wsum, off, 64);
  if (l == 0)
    atomicAdd(out, wsum * (1.0f / ((float)NPTS * (float)(FCH - 1))));
}

extern "C" void kernel_launch(void* const* d_in, const int* in_sizes, int n_in,
                              void* d_out, int out_size, void* d_ws, size_t ws_size,
                              hipStream_t stream) {
  const float* x     = (const float*)d_in[0];
  const float* omega = (const float*)d_in[1];
  const float* W1    = (const float*)d_in[2];
  const float* b1    = (const float*)d_in[3];
  const float* W2    = (const float*)d_in[4];
  const float* b2    = (const float*)d_in[5];
  const float* W3    = (const float*)d_in[6];
  const float* b3    = (const float*)d_in[7];
  float* out = (float*)d_out;

  (void)hipMemsetAsync(out, 0, sizeof(float), stream);
  helmholtz_kernel<<<GRID, BLOCK, 0, stream>>>(x, omega, W1, b1, W2, b2, W3, b3, out);
}